// Round 4
// baseline (157.048 us; speedup 1.0000x reference)
//
#include <hip/hip_runtime.h>
#include <math.h>

#define NPOS   1024
#define CIN    256
#define DQKV   1536
#define ATTND  512
#define HEADS  8
#define DH     64
#define COUT   256
#define NBATCH 8
#define SCALE  0.125f
#define GN_EPS 1e-5f

typedef __attribute__((ext_vector_type(8))) __bf16 bf16x8;
typedef __attribute__((ext_vector_type(4))) __bf16 bf16x4;
typedef __attribute__((ext_vector_type(4))) float floatx4;
typedef __attribute__((ext_vector_type(8))) unsigned short ushort8;

#if __has_builtin(__builtin_amdgcn_exp2f)
#define EXP2(x) __builtin_amdgcn_exp2f(x)
#else
#define EXP2(x) exp2f(x)
#endif

// ws byte layout:
//   xb    bf16 [8192][256]          @ 0        (x pre-converted to bf16)
//   wT    bf16 [1536][256]          @ 4 MiB    (SCALE*log2e folded into cols<512)
//   woT   bf16 [256][512]           @ 4.75 MiB
//   qb    bf16 [B][H][1024][64]     @ 5 MiB
//   kb    bf16 same                 @ 13 MiB
//   vT    bf16 [B][H][64][1024]     @ 29 MiB
//   o2tT  bf16 [B][1024][512]       @ 45 MiB
//   stats fp32 [256]                @ 53 MiB   sum[b]@b*16, sq[b]@128+b*16, cnt@u32[248]
#define OFF_XB   (0ull)
#define OFF_WT   (4ull*1048576)
#define OFF_WOT  (4ull*1048576 + 786432ull)
#define OFF_QB   (5ull*1048576)
#define OFF_KB   (13ull*1048576)
#define OFF_VT   (29ull*1048576)
#define OFF_O2TT (45ull*1048576)
#define OFF_ST   (53ull*1048576)

__device__ inline ushort8 cvt_bf8(float4 a, float4 b) {
    bf16x8 o;
    o[0] = (__bf16)a.x; o[1] = (__bf16)a.y; o[2] = (__bf16)a.z; o[3] = (__bf16)a.w;
    o[4] = (__bf16)b.x; o[5] = (__bf16)b.y; o[6] = (__bf16)b.z; o[7] = (__bf16)b.w;
    return *(ushort8*)&o;
}

// ---------------- prep: weight + x conversions (+ zero stats) ----------------
__global__ __launch_bounds__(256) void prep(
    const float* __restrict__ x,
    const float* __restrict__ w_qkv, const float* __restrict__ w_out,
    unsigned short* __restrict__ xb,
    unsigned short* __restrict__ wT, unsigned short* __restrict__ woT,
    float* __restrict__ stats)
{
    const int bid = blockIdx.x;
    const int t = threadIdx.x;
    __shared__ unsigned short tile[64][68];

    if (bid == 0) stats[t] = 0.0f;

    if (bid >= 128) {   // x -> bf16 (elementwise, any order)
        const size_t base = (size_t)(bid - 128) * 8192 + (size_t)t * 8;
        #pragma unroll
        for (int i = 0; i < 4; ++i) {
            const size_t off = base + (size_t)i * 2048;
            const float4 u = *(const float4*)&x[off];
            const float4 v = *(const float4*)&x[off + 4];
            *(ushort8*)&xb[off] = cvt_bf8(u, v);
        }
        return;
    }

    if (bid < 96) {
        const int n0 = (bid >> 2) * 64, k0 = (bid & 3) * 64;
        #pragma unroll
        for (int p = 0; p < 4; ++p) {
            const int row = p * 16 + (t >> 4);
            const int c = (t & 15) * 4;
            float4 a = *(const float4*)&w_qkv[(size_t)(k0 + row) * DQKV + n0 + c];
            float sv[4] = {a.x, a.y, a.z, a.w};
            #pragma unroll
            for (int j = 0; j < 4; ++j) {
                // fold softmax scale AND log2(e) into Q columns: attn uses raw v_exp_f32 (2^x)
                const float sc = (n0 + c + j) < 512 ? (SCALE * 1.44269504088896f) : 1.0f;
                __bf16 hb = (__bf16)(sv[j] * sc);
                tile[row][c + j] = *(unsigned short*)&hb;
            }
        }
        __syncthreads();
        const int nn = t >> 2;
        const int kc = (t & 3) * 16;
        unsigned short tmp[16];
        #pragma unroll
        for (int j = 0; j < 16; ++j) tmp[j] = tile[kc + j][nn];
        *(ushort8*)&wT[(size_t)(n0 + nn) * 256 + k0 + kc]     = *(ushort8*)&tmp[0];
        *(ushort8*)&wT[(size_t)(n0 + nn) * 256 + k0 + kc + 8] = *(ushort8*)&tmp[8];
        return;
    }

    const int idx = bid - 96;
    const int d0 = (idx & 3) * 64, k0 = (idx >> 2) * 64;
    #pragma unroll
    for (int p = 0; p < 4; ++p) {
        const int row = p * 16 + (t >> 4);
        const int c = (t & 15) * 4;
        float4 a = *(const float4*)&w_out[(size_t)(k0 + row) * COUT + d0 + c];
        float sv[4] = {a.x, a.y, a.z, a.w};
        #pragma unroll
        for (int j = 0; j < 4; ++j) {
            __bf16 hb = (__bf16)sv[j];
            tile[row][c + j] = *(unsigned short*)&hb;
        }
    }
    __syncthreads();
    {
        const int nn = t >> 2;
        const int kc = (t & 3) * 16;
        unsigned short tmp[16];
        #pragma unroll
        for (int j = 0; j < 16; ++j) tmp[j] = tile[kc + j][nn];
        *(ushort8*)&woT[(size_t)(d0 + nn) * 512 + k0 + kc]     = *(ushort8*)&tmp[0];
        *(ushort8*)&woT[(size_t)(d0 + nn) * 512 + k0 + kc + 8] = *(ushort8*)&tmp[8];
    }
}

// ---------------- kernel A: QKV GEMM, bf16 MFMA (bf16 x via prep) ----------------
__global__ __launch_bounds__(256) void qkv_gemm_mfma(
    const unsigned short* __restrict__ xb, const __bf16* __restrict__ wT,
    __bf16* __restrict__ qb, __bf16* __restrict__ kb, __bf16* __restrict__ vT)
{
    const int bid = blockIdx.x;
    // XCD swizzle: each XCD owns 8 consecutive m-tiles x all 12 n-tiles
    const int xcd = bid & 7, local = bid >> 3;           // local 0..95
    const int m0 = (xcd * 8 + (local & 7)) * 128;
    const int n0 = (local >> 3) * 128;

    const int t = threadIdx.x;
    const int w = t >> 6, lane = t & 63;
    const int col = lane & 15, qd = lane >> 4;
    const int wm = w >> 1, wn = w & 1;

    __shared__ __align__(16) unsigned short As[128][40];
    __shared__ __align__(16) unsigned short Bs[128][40];

    floatx4 zero4 = {0.f, 0.f, 0.f, 0.f};
    floatx4 acc[4][4];
    #pragma unroll
    for (int i = 0; i < 4; ++i)
        #pragma unroll
        for (int j = 0; j < 4; ++j) acc[i][j] = zero4;

    const int lrow = t >> 2, lc8 = (t & 3) * 8;

    ushort8 areg[2], breg[2];
    areg[0] = *(const ushort8*)&xb[(size_t)(m0 + lrow) * 256 + lc8];
    areg[1] = *(const ushort8*)&xb[(size_t)(m0 + lrow + 64) * 256 + lc8];
    breg[0] = *(const ushort8*)&wT[(size_t)(n0 + lrow) * 256 + lc8];
    breg[1] = *(const ushort8*)&wT[(size_t)(n0 + lrow + 64) * 256 + lc8];

    for (int kk = 0; kk < 8; ++kk) {
        __syncthreads();
        *(ushort8*)&As[lrow][lc8]      = areg[0];
        *(ushort8*)&As[lrow + 64][lc8] = areg[1];
        *(ushort8*)&Bs[lrow][lc8]      = breg[0];
        *(ushort8*)&Bs[lrow + 64][lc8] = breg[1];
        __syncthreads();
        const int kn = (kk < 7) ? (kk + 1) * 32 : 0;
        areg[0] = *(const ushort8*)&xb[(size_t)(m0 + lrow) * 256 + kn + lc8];
        areg[1] = *(const ushort8*)&xb[(size_t)(m0 + lrow + 64) * 256 + kn + lc8];
        breg[0] = *(const ushort8*)&wT[(size_t)(n0 + lrow) * 256 + kn + lc8];
        breg[1] = *(const ushort8*)&wT[(size_t)(n0 + lrow + 64) * 256 + kn + lc8];

        bf16x8 wf[4];
        #pragma unroll
        for (int ct = 0; ct < 4; ++ct)
            wf[ct] = *(const bf16x8*)&Bs[wn * 64 + ct * 16 + col][qd * 8];
        #pragma unroll
        for (int st = 0; st < 4; ++st) {
            bf16x8 xf = *(const bf16x8*)&As[wm * 64 + st * 16 + col][qd * 8];
            #pragma unroll
            for (int ct = 0; ct < 4; ++ct)
                acc[ct][st] = __builtin_amdgcn_mfma_f32_16x16x32_bf16(wf[ct], xf, acc[ct][st], 0, 0, 0);
        }
    }

    #pragma unroll
    for (int ct = 0; ct < 4; ++ct) {
        const int cbase = n0 + wn * 64 + ct * 16;
        const int sect = cbase >> 9;
        const int hh = (cbase >> 6) & 7;
        const int dd = (cbase & 63) + qd * 4;
        if (sect < 2) {
            __bf16* base = (sect == 0) ? qb : kb;
            #pragma unroll
            for (int st = 0; st < 4; ++st) {
                const int m = m0 + wm * 64 + st * 16 + col;
                const int b_ = m >> 10, n = m & 1023;
                bf16x4 o;
                #pragma unroll
                for (int r = 0; r < 4; ++r) o[r] = (__bf16)acc[ct][st][r];
                *(bf16x4*)&base[(((size_t)b_ * HEADS + hh) * NPOS + n) * DH + dd] = o;
            }
        } else {
            #pragma unroll
            for (int st = 0; st < 4; ++st) {
                const int m = m0 + wm * 64 + st * 16 + col;
                const int b_ = m >> 10, n = m & 1023;
                const size_t rowbase = ((size_t)(b_ * HEADS + hh) * DH + dd) * NPOS + n;
                #pragma unroll
                for (int r = 0; r < 4; ++r)
                    vT[rowbase + (size_t)r * NPOS] = (__bf16)acc[ct][st][r];
            }
        }
    }
}

// ---------------- kernel B: flash attention v3, TQ=64, 4 blocks/CU ----------------
// o2tT channel mapping (faithful reshape): ch = h*64 + (n>>4), p = (n&15)*64 + d.
// With n = qblk*64 + w*16 + qq: ch = h*64 + qblk*4 + w (wave-constant), p = qq*64 + d.
__global__ __launch_bounds__(256, 4) void attn_mfma(
    const __bf16* __restrict__ qg, const __bf16* __restrict__ kg,
    const __bf16* __restrict__ vTg, __bf16* __restrict__ o2tT)
{
    const int bid = blockIdx.x;
    // XCD swizzle: 16 qblks of one bh co-located per XCD (2 MB K/V resident in L2)
    const int rid = (bid & 7) * 128 + (bid >> 3);
    const int qblk = rid & 15, h = (rid >> 4) & 7, b = rid >> 7;
    const int bh = b * HEADS + h;
    const int t = threadIdx.x;
    const int w = t >> 6, lane = t & 63;
    const int col = lane & 15, qd = lane >> 4;

    __shared__ __align__(16) unsigned short Ks[64][64];    // K[n][d], XOR-swizzled rows
    __shared__ __align__(16) unsigned short Vs[64][64];    // V^T[d][n], XOR-swizzled rows
    __shared__ __align__(16) unsigned short ps[4][16][72]; // per-wave P / O^T buffer

    // Q in registers: q = qblk*64 + w*16 + col
    const __bf16* qptr = qg + ((size_t)bh * NPOS + qblk * 64 + w * 16 + col) * DH;
    bf16x8 qf0 = *(const bf16x8*)(qptr + qd * 8);
    bf16x8 qf1 = *(const bf16x8*)(qptr + 32 + qd * 8);

    const char* kByte = (const char*)kg  + (size_t)bh * NPOS * DH * 2;
    const char* vByte = (const char*)vTg + (size_t)bh * DH * NPOS * 2;

    // reg-staging geometry: thread covers rows row0, row0+8; 8 lanes x 16B per row
    const int row0 = w * 16 + (lane >> 3);
    const int seg  = lane & 7;
    const char* ksrc = kByte + (size_t)row0 * 128  + seg * 16;   // K rows stride 128B
    const char* vsrc = vByte + (size_t)row0 * 2048 + seg * 16;   // V^T rows stride 2048B
    const int swzo = (seg * 16) ^ ((row0 & 7) << 4);             // same for row0 and row0+8
    unsigned short* kw0 = (unsigned short*)((char*)&Ks[row0][0] + swzo);
    unsigned short* kw1 = (unsigned short*)((char*)&Ks[row0 + 8][0] + swzo);
    unsigned short* vw0 = (unsigned short*)((char*)&Vs[row0][0] + swzo);
    unsigned short* vw1 = (unsigned short*)((char*)&Vs[row0 + 8][0] + swzo);

    ushort8 kreg[2], vreg[2];
    kreg[0] = *(const ushort8*)(ksrc);
    kreg[1] = *(const ushort8*)(ksrc + 1024);
    vreg[0] = *(const ushort8*)(vsrc);
    vreg[1] = *(const ushort8*)(vsrc + 16384);

    floatx4 zero4 = {0.f, 0.f, 0.f, 0.f};
    floatx4 accO[4] = {zero4, zero4, zero4, zero4};
    floatx4 accL = zero4;
    bf16x8 ones8;
    #pragma unroll
    for (int j = 0; j < 8; ++j) ones8[j] = (__bf16)1.0f;

    for (int kt = 0; kt < 16; ++kt) {
        __syncthreads();                      // previous tile fully consumed
        *(ushort8*)kw0 = kreg[0];
        *(ushort8*)kw1 = kreg[1];
        *(ushort8*)vw0 = vreg[0];
        *(ushort8*)vw1 = vreg[1];
        __syncthreads();                      // tile ready
        if (kt < 15) {                        // T14: issue next-tile loads under compute
            kreg[0] = *(const ushort8*)(ksrc + (size_t)(kt + 1) * 8192);
            kreg[1] = *(const ushort8*)(ksrc + (size_t)(kt + 1) * 8192 + 1024);
            vreg[0] = *(const ushort8*)(vsrc + (size_t)(kt + 1) * 128);
            vreg[1] = *(const ushort8*)(vsrc + (size_t)(kt + 1) * 128 + 16384);
        }

        floatx4 accS[4];
        #pragma unroll
        for (int mt = 0; mt < 4; ++mt) {
            const int kr = mt * 16 + col;
            const char* krow = (const char*)&Ks[kr][0];
            const int rsw = (kr & 7) << 4;
            bf16x8 kf0 = *(const bf16x8*)(krow + ((qd * 16) ^ rsw));
            bf16x8 kf1 = *(const bf16x8*)(krow + ((64 + qd * 16) ^ rsw));
            accS[mt] = __builtin_amdgcn_mfma_f32_16x16x32_bf16(kf0, qf0, zero4, 0, 0, 0);
            accS[mt] = __builtin_amdgcn_mfma_f32_16x16x32_bf16(kf1, qf1, accS[mt], 0, 0, 0);
        }

        #pragma unroll
        for (int mt = 0; mt < 4; ++mt) {
            bf16x4 pv;
            #pragma unroll
            for (int r = 0; r < 4; ++r) pv[r] = (__bf16)EXP2(accS[mt][r]);
            *(bf16x4*)&ps[w][col][mt * 16 + qd * 4] = pv;
        }

        bf16x8 pf0 = *(const bf16x8*)&ps[w][col][qd * 8];
        bf16x8 pf1 = *(const bf16x8*)&ps[w][col][32 + qd * 8];
        accL = __builtin_amdgcn_mfma_f32_16x16x32_bf16(ones8, pf0, accL, 0, 0, 0);
        accL = __builtin_amdgcn_mfma_f32_16x16x32_bf16(ones8, pf1, accL, 0, 0, 0);

        #pragma unroll
        for (int ct = 0; ct < 4; ++ct) {
            const int vr = ct * 16 + col;
            const char* vrow = (const char*)&Vs[vr][0];
            const int rsw = (vr & 7) << 4;
            bf16x8 vf0 = *(const bf16x8*)(vrow + ((qd * 16) ^ rsw));
            bf16x8 vf1 = *(const bf16x8*)(vrow + ((64 + qd * 16) ^ rsw));
            accO[ct] = __builtin_amdgcn_mfma_f32_16x16x32_bf16(vf0, pf0, accO[ct], 0, 0, 0);
            accO[ct] = __builtin_amdgcn_mfma_f32_16x16x32_bf16(vf1, pf1, accO[ct], 0, 0, 0);
        }
    }

    const float inv_l = 1.0f / accL[0];

    // deposit O^T per wave: ps[w][q=col][d]
    #pragma unroll
    for (int ct = 0; ct < 4; ++ct) {
        bf16x4 o;
        #pragma unroll
        for (int r = 0; r < 4; ++r) o[r] = (__bf16)(accO[ct][r] * inv_l);
        *(bf16x4*)&ps[w][col][ct * 16 + qd * 4] = o;
    }
    __syncthreads();
    // gather across wave planes: channel cb+j <- wave j; p = qq*64 + d
    const int cb = h * 64 + qblk * 4;
    #pragma unroll
    for (int i = 0; i < 4; ++i) {
        const int p = i * 256 + t;
        const int qq = p >> 6, dd = p & 63;
        bf16x4 o;
        #pragma unroll
        for (int j = 0; j < 4; ++j) {
            unsigned short u = ps[j][qq][dd];
            o[j] = *(__bf16*)&u;
        }
        *(bf16x4*)&o2tT[((size_t)b * NPOS + p) * ATTND + cb] = o;
    }
}

// ---------------- kernel C: output GEMM + bias + GN stats + global barrier + normalize ----------------
__global__ __launch_bounds__(256, 2) void out_mfma(
    const __bf16* __restrict__ a, const __bf16* __restrict__ woT,
    const float* __restrict__ b_out, const float* __restrict__ gamma,
    const float* __restrict__ beta, float* __restrict__ y,
    float* __restrict__ stats)
{
    const int bid = blockIdx.x;
    // XCD swizzle: each XCD owns one batch b (16 m-tiles x 4 d-tiles)
    const int xcd = bid & 7, local = bid >> 3;            // local 0..63
    const int m0 = (xcd * 16 + (local & 15)) * 64;
    const int d0 = (local >> 4) * 64;
    const int b = xcd;

    const int t = threadIdx.x;
    const int w = t >> 6, lane = t & 63;
    const int col = lane & 15, qd = lane >> 4;
    const int wm = w >> 1, wn = w & 1;

    __shared__ __align__(16) unsigned short As[64][72];
    __shared__ __align__(16) unsigned short Bs[64][72];
    __shared__ float reds[4], redq[4];
    __shared__ float sh_mean, sh_rsig;

    floatx4 zero4 = {0.f, 0.f, 0.f, 0.f};
    floatx4 acc[2][2];
    #pragma unroll
    for (int i = 0; i < 2; ++i)
        #pragma unroll
        for (int j = 0; j < 2; ++j) acc[i][j] = zero4;

    const int lrow = t >> 2, lc = (t & 3) * 16;

    for (int k0 = 0; k0 < ATTND; k0 += 64) {
        __syncthreads();
        *(ushort8*)&As[lrow][lc]     = *(const ushort8*)&a[(size_t)(m0 + lrow) * ATTND + k0 + lc];
        *(ushort8*)&As[lrow][lc + 8] = *(const ushort8*)&a[(size_t)(m0 + lrow) * ATTND + k0 + lc + 8];
        *(ushort8*)&Bs[lrow][lc]     = *(const ushort8*)&woT[(size_t)(d0 + lrow) * ATTND + k0 + lc];
        *(ushort8*)&Bs[lrow][lc + 8] = *(const ushort8*)&woT[(size_t)(d0 + lrow) * ATTND + k0 + lc + 8];
        __syncthreads();
        bf16x8 af0[2], af1[2];
        #pragma unroll
        for (int mt = 0; mt < 2; ++mt) {
            af0[mt] = *(const bf16x8*)&As[wm * 32 + mt * 16 + col][qd * 8];
            af1[mt] = *(const bf16x8*)&As[wm * 32 + mt * 16 + col][32 + qd * 8];
        }
        #pragma unroll
        for (int nt = 0; nt < 2; ++nt) {
            bf16x8 bf0 = *(const bf16x8*)&Bs[wn * 32 + nt * 16 + col][qd * 8];
            bf16x8 bf1 = *(const bf16x8*)&Bs[wn * 32 + nt * 16 + col][32 + qd * 8];
            #pragma unroll
            for (int mt = 0; mt < 2; ++mt) {
                acc[mt][nt] = __builtin_amdgcn_mfma_f32_16x16x32_bf16(af0[mt], bf0, acc[mt][nt], 0, 0, 0);
                acc[mt][nt] = __builtin_amdgcn_mfma_f32_16x16x32_bf16(af1[mt], bf1, acc[mt][nt], 0, 0, 0);
            }
        }
    }

    float bias_n[2], g_n[2], bt_n[2];
    #pragma unroll
    for (int nt = 0; nt < 2; ++nt) {
        const int d = d0 + wn * 32 + nt * 16 + col;
        bias_n[nt] = b_out[d];
        g_n[nt]    = gamma[d];
        bt_n[nt]   = beta[d];
    }

    // pre-norm values kept in registers; stats accumulated
    float bsum = 0.0f, bsq = 0.0f;
    #pragma unroll
    for (int mt = 0; mt < 2; ++mt)
        #pragma unroll
        for (int nt = 0; nt < 2; ++nt)
            #pragma unroll
            for (int r = 0; r < 4; ++r) {
                const float v = acc[mt][nt][r] + bias_n[nt];
                acc[mt][nt][r] = v;
                bsum += v;
                bsq  += v * v;
            }
    #pragma unroll
    for (int off = 1; off < 64; off <<= 1) {
        bsum += __shfl_xor(bsum, off);
        bsq  += __shfl_xor(bsq, off);
    }
    if (lane == 0) { reds[w] = bsum; redq[w] = bsq; }
    __syncthreads();

    // global barrier: 512 blocks, guaranteed 2/CU co-resident (LDS ~37K, VGPR<=256/wave)
    unsigned* cnt = (unsigned*)stats + 248;
    if (t == 0) {
        atomicAdd(&stats[b * 16],       reds[0] + reds[1] + reds[2] + reds[3]);
        atomicAdd(&stats[128 + b * 16], redq[0] + redq[1] + redq[2] + redq[3]);
        __threadfence();
        atomicAdd(cnt, 1u);
        int guard = 0;
        while (__hip_atomic_load(cnt, __ATOMIC_ACQUIRE, __HIP_MEMORY_SCOPE_AGENT) < 512u) {
            __builtin_amdgcn_s_sleep(8);
            if (++guard > 2000000) break;   // hang insurance (never triggers legitimately)
        }
        const float invn = 1.0f / (float)(NPOS * COUT);
        const float mean = __hip_atomic_load(&stats[b * 16], __ATOMIC_RELAXED, __HIP_MEMORY_SCOPE_AGENT) * invn;
        const float msq  = __hip_atomic_load(&stats[128 + b * 16], __ATOMIC_RELAXED, __HIP_MEMORY_SCOPE_AGENT) * invn;
        sh_mean = mean;
        sh_rsig = rsqrtf(msq - mean * mean + GN_EPS);
    }
    __syncthreads();

    const float mean = sh_mean, rsig = sh_rsig;

    #pragma unroll
    for (int mt = 0; mt < 2; ++mt) {
        #pragma unroll
        for (int r = 0; r < 4; ++r) {
            const int m = m0 + wm * 32 + mt * 16 + qd * 4 + r;
            const int p = m & 1023;
            #pragma unroll
            for (int nt = 0; nt < 2; ++nt) {
                const int d = d0 + wn * 32 + nt * 16 + col;
                const float v = (acc[mt][nt][r] - mean) * rsig * g_n[nt] + bt_n[nt];
                y[((size_t)b * NPOS + p) * COUT + d] = v;
            }
        }
    }
}

extern "C" void kernel_launch(void* const* d_in, const int* in_sizes, int n_in,
                              void* d_out, int out_size, void* d_ws, size_t ws_size,
                              hipStream_t stream)
{
    const float* x     = (const float*)d_in[0];
    const float* w_qkv = (const float*)d_in[1];
    const float* w_out = (const float*)d_in[2];
    const float* b_out = (const float*)d_in[3];
    const float* gamma = (const float*)d_in[4];
    const float* beta  = (const float*)d_in[5];
    float* out = (float*)d_out;
    char* ws = (char*)d_ws;

    unsigned short* xb  = (unsigned short*)(ws + OFF_XB);
    unsigned short* wT  = (unsigned short*)(ws + OFF_WT);
    unsigned short* woT = (unsigned short*)(ws + OFF_WOT);
    __bf16* qb  = (__bf16*)(ws + OFF_QB);
    __bf16* kb  = (__bf16*)(ws + OFF_KB);
    __bf16* vT  = (__bf16*)(ws + OFF_VT);
    __bf16* o2tT = (__bf16*)(ws + OFF_O2TT);
    float* stats = (float*)(ws + OFF_ST);

    prep         <<<dim3(384),  256, 0, stream>>>(x, w_qkv, w_out, xb, wT, woT, stats);
    qkv_gemm_mfma<<<dim3(768),  256, 0, stream>>>(xb, (const __bf16*)wT, qb, kb, vT);
    attn_mfma    <<<dim3(1024), 256, 0, stream>>>(qb, kb, vT, o2tT);
    out_mfma     <<<dim3(512),  256, 0, stream>>>(o2tT, (const __bf16*)woT, b_out, gamma, beta, out, stats);
}

// Round 5
// 128.600 us; speedup vs baseline: 1.2212x; 1.2212x over previous
//
#include <hip/hip_runtime.h>
#include <math.h>

#define NPOS   1024
#define CIN    256
#define DQKV   1536
#define ATTND  512
#define HEADS  8
#define DH     64
#define COUT   256
#define NBATCH 8
#define SCALE  0.125f
#define GN_EPS 1e-5f

typedef __attribute__((ext_vector_type(8))) __bf16 bf16x8;
typedef __attribute__((ext_vector_type(4))) __bf16 bf16x4;
typedef __attribute__((ext_vector_type(4))) float floatx4;
typedef __attribute__((ext_vector_type(8))) unsigned short ushort8;

#if __has_builtin(__builtin_amdgcn_exp2f)
#define EXP2(x) __builtin_amdgcn_exp2f(x)
#else
#define EXP2(x) exp2f(x)
#endif

// ws byte layout:
//   xb    bf16 [8192][256]          @ 0        (x pre-converted to bf16)
//   wT    bf16 [1536][256]          @ 4 MiB    (SCALE*log2e folded into cols<512)
//   woT   bf16 [256][512]           @ 4.75 MiB
//   qb    bf16 [B][H][1024][64]     @ 5 MiB
//   kb    bf16 same                 @ 13 MiB
//   vT    bf16 [B][H][64][1024]     @ 29 MiB
//   o2tT  bf16 [B][1024][512]       @ 45 MiB
//   stats fp32 [256]                @ 53 MiB   sum[b]@b*16, sq[b]@128+b*16
#define OFF_XB   (0ull)
#define OFF_WT   (4ull*1048576)
#define OFF_WOT  (4ull*1048576 + 786432ull)
#define OFF_QB   (5ull*1048576)
#define OFF_KB   (13ull*1048576)
#define OFF_VT   (29ull*1048576)
#define OFF_O2TT (45ull*1048576)
#define OFF_ST   (53ull*1048576)

__device__ inline ushort8 cvt_bf8(float4 a, float4 b) {
    bf16x8 o;
    o[0] = (__bf16)a.x; o[1] = (__bf16)a.y; o[2] = (__bf16)a.z; o[3] = (__bf16)a.w;
    o[4] = (__bf16)b.x; o[5] = (__bf16)b.y; o[6] = (__bf16)b.z; o[7] = (__bf16)b.w;
    return *(ushort8*)&o;
}

// ---------------- prep: weight + x conversions (+ zero stats) ----------------
__global__ __launch_bounds__(256) void prep(
    const float* __restrict__ x,
    const float* __restrict__ w_qkv, const float* __restrict__ w_out,
    unsigned short* __restrict__ xb,
    unsigned short* __restrict__ wT, unsigned short* __restrict__ woT,
    float* __restrict__ stats)
{
    const int bid = blockIdx.x;
    const int t = threadIdx.x;
    __shared__ unsigned short tile[64][68];

    if (bid == 0) stats[t] = 0.0f;

    if (bid >= 128) {   // x -> bf16 (elementwise, any order)
        const size_t base = (size_t)(bid - 128) * 8192 + (size_t)t * 8;
        #pragma unroll
        for (int i = 0; i < 4; ++i) {
            const size_t off = base + (size_t)i * 2048;
            const float4 u = *(const float4*)&x[off];
            const float4 v = *(const float4*)&x[off + 4];
            *(ushort8*)&xb[off] = cvt_bf8(u, v);
        }
        return;
    }

    if (bid < 96) {
        const int n0 = (bid >> 2) * 64, k0 = (bid & 3) * 64;
        #pragma unroll
        for (int p = 0; p < 4; ++p) {
            const int row = p * 16 + (t >> 4);
            const int c = (t & 15) * 4;
            float4 a = *(const float4*)&w_qkv[(size_t)(k0 + row) * DQKV + n0 + c];
            float sv[4] = {a.x, a.y, a.z, a.w};
            #pragma unroll
            for (int j = 0; j < 4; ++j) {
                // fold softmax scale AND log2(e) into Q columns: attn uses raw v_exp_f32 (2^x)
                const float sc = (n0 + c + j) < 512 ? (SCALE * 1.44269504088896f) : 1.0f;
                __bf16 hb = (__bf16)(sv[j] * sc);
                tile[row][c + j] = *(unsigned short*)&hb;
            }
        }
        __syncthreads();
        const int nn = t >> 2;
        const int kc = (t & 3) * 16;
        unsigned short tmp[16];
        #pragma unroll
        for (int j = 0; j < 16; ++j) tmp[j] = tile[kc + j][nn];
        *(ushort8*)&wT[(size_t)(n0 + nn) * 256 + k0 + kc]     = *(ushort8*)&tmp[0];
        *(ushort8*)&wT[(size_t)(n0 + nn) * 256 + k0 + kc + 8] = *(ushort8*)&tmp[8];
        return;
    }

    const int idx = bid - 96;
    const int d0 = (idx & 3) * 64, k0 = (idx >> 2) * 64;
    #pragma unroll
    for (int p = 0; p < 4; ++p) {
        const int row = p * 16 + (t >> 4);
        const int c = (t & 15) * 4;
        float4 a = *(const float4*)&w_out[(size_t)(k0 + row) * COUT + d0 + c];
        float sv[4] = {a.x, a.y, a.z, a.w};
        #pragma unroll
        for (int j = 0; j < 4; ++j) {
            __bf16 hb = (__bf16)sv[j];
            tile[row][c + j] = *(unsigned short*)&hb;
        }
    }
    __syncthreads();
    {
        const int nn = t >> 2;
        const int kc = (t & 3) * 16;
        unsigned short tmp[16];
        #pragma unroll
        for (int j = 0; j < 16; ++j) tmp[j] = tile[kc + j][nn];
        *(ushort8*)&woT[(size_t)(d0 + nn) * 512 + k0 + kc]     = *(ushort8*)&tmp[0];
        *(ushort8*)&woT[(size_t)(d0 + nn) * 512 + k0 + kc + 8] = *(ushort8*)&tmp[8];
    }
}

// ---------------- kernel A: QKV GEMM, bf16 MFMA (bf16 x via prep) ----------------
__global__ __launch_bounds__(256) void qkv_gemm_mfma(
    const unsigned short* __restrict__ xb, const __bf16* __restrict__ wT,
    __bf16* __restrict__ qb, __bf16* __restrict__ kb, __bf16* __restrict__ vT)
{
    const int bid = blockIdx.x;
    // XCD swizzle: each XCD owns 8 consecutive m-tiles x all 12 n-tiles
    const int xcd = bid & 7, local = bid >> 3;           // local 0..95
    const int m0 = (xcd * 8 + (local & 7)) * 128;
    const int n0 = (local >> 3) * 128;

    const int t = threadIdx.x;
    const int w = t >> 6, lane = t & 63;
    const int col = lane & 15, qd = lane >> 4;
    const int wm = w >> 1, wn = w & 1;

    __shared__ __align__(16) unsigned short As[128][40];
    __shared__ __align__(16) unsigned short Bs[128][40];

    floatx4 zero4 = {0.f, 0.f, 0.f, 0.f};
    floatx4 acc[4][4];
    #pragma unroll
    for (int i = 0; i < 4; ++i)
        #pragma unroll
        for (int j = 0; j < 4; ++j) acc[i][j] = zero4;

    const int lrow = t >> 2, lc8 = (t & 3) * 8;

    ushort8 areg[2], breg[2];
    areg[0] = *(const ushort8*)&xb[(size_t)(m0 + lrow) * 256 + lc8];
    areg[1] = *(const ushort8*)&xb[(size_t)(m0 + lrow + 64) * 256 + lc8];
    breg[0] = *(const ushort8*)&wT[(size_t)(n0 + lrow) * 256 + lc8];
    breg[1] = *(const ushort8*)&wT[(size_t)(n0 + lrow + 64) * 256 + lc8];

    for (int kk = 0; kk < 8; ++kk) {
        __syncthreads();
        *(ushort8*)&As[lrow][lc8]      = areg[0];
        *(ushort8*)&As[lrow + 64][lc8] = areg[1];
        *(ushort8*)&Bs[lrow][lc8]      = breg[0];
        *(ushort8*)&Bs[lrow + 64][lc8] = breg[1];
        __syncthreads();
        const int kn = (kk < 7) ? (kk + 1) * 32 : 0;
        areg[0] = *(const ushort8*)&xb[(size_t)(m0 + lrow) * 256 + kn + lc8];
        areg[1] = *(const ushort8*)&xb[(size_t)(m0 + lrow + 64) * 256 + kn + lc8];
        breg[0] = *(const ushort8*)&wT[(size_t)(n0 + lrow) * 256 + kn + lc8];
        breg[1] = *(const ushort8*)&wT[(size_t)(n0 + lrow + 64) * 256 + kn + lc8];

        bf16x8 wf[4];
        #pragma unroll
        for (int ct = 0; ct < 4; ++ct)
            wf[ct] = *(const bf16x8*)&Bs[wn * 64 + ct * 16 + col][qd * 8];
        #pragma unroll
        for (int st = 0; st < 4; ++st) {
            bf16x8 xf = *(const bf16x8*)&As[wm * 64 + st * 16 + col][qd * 8];
            #pragma unroll
            for (int ct = 0; ct < 4; ++ct)
                acc[ct][st] = __builtin_amdgcn_mfma_f32_16x16x32_bf16(wf[ct], xf, acc[ct][st], 0, 0, 0);
        }
    }

    #pragma unroll
    for (int ct = 0; ct < 4; ++ct) {
        const int cbase = n0 + wn * 64 + ct * 16;
        const int sect = cbase >> 9;
        const int hh = (cbase >> 6) & 7;
        const int dd = (cbase & 63) + qd * 4;
        if (sect < 2) {
            __bf16* base = (sect == 0) ? qb : kb;
            #pragma unroll
            for (int st = 0; st < 4; ++st) {
                const int m = m0 + wm * 64 + st * 16 + col;
                const int b_ = m >> 10, n = m & 1023;
                bf16x4 o;
                #pragma unroll
                for (int r = 0; r < 4; ++r) o[r] = (__bf16)acc[ct][st][r];
                *(bf16x4*)&base[(((size_t)b_ * HEADS + hh) * NPOS + n) * DH + dd] = o;
            }
        } else {
            #pragma unroll
            for (int st = 0; st < 4; ++st) {
                const int m = m0 + wm * 64 + st * 16 + col;
                const int b_ = m >> 10, n = m & 1023;
                const size_t rowbase = ((size_t)(b_ * HEADS + hh) * DH + dd) * NPOS + n;
                #pragma unroll
                for (int r = 0; r < 4; ++r)
                    vT[rowbase + (size_t)r * NPOS] = (__bf16)acc[ct][st][r];
            }
        }
    }
}

// ---------------- kernel B: flash attention v3, TQ=64, 4 blocks/CU ----------------
// o2tT channel mapping (faithful reshape): ch = h*64 + (n>>4), p = (n&15)*64 + d.
// With n = qblk*64 + w*16 + qq: ch = h*64 + qblk*4 + w (wave-constant), p = qq*64 + d.
__global__ __launch_bounds__(256, 4) void attn_mfma(
    const __bf16* __restrict__ qg, const __bf16* __restrict__ kg,
    const __bf16* __restrict__ vTg, __bf16* __restrict__ o2tT)
{
    const int bid = blockIdx.x;
    // XCD swizzle: 16 qblks of one bh co-located per XCD (2 MB K/V resident in L2)
    const int rid = (bid & 7) * 128 + (bid >> 3);
    const int qblk = rid & 15, h = (rid >> 4) & 7, b = rid >> 7;
    const int bh = b * HEADS + h;
    const int t = threadIdx.x;
    const int w = t >> 6, lane = t & 63;
    const int col = lane & 15, qd = lane >> 4;

    __shared__ __align__(16) unsigned short Ks[64][64];    // K[n][d], XOR-swizzled rows
    __shared__ __align__(16) unsigned short Vs[64][64];    // V^T[d][n], XOR-swizzled rows
    __shared__ __align__(16) unsigned short ps[4][16][72]; // per-wave P / O^T buffer

    // Q in registers: q = qblk*64 + w*16 + col
    const __bf16* qptr = qg + ((size_t)bh * NPOS + qblk * 64 + w * 16 + col) * DH;
    bf16x8 qf0 = *(const bf16x8*)(qptr + qd * 8);
    bf16x8 qf1 = *(const bf16x8*)(qptr + 32 + qd * 8);

    const char* kByte = (const char*)kg  + (size_t)bh * NPOS * DH * 2;
    const char* vByte = (const char*)vTg + (size_t)bh * DH * NPOS * 2;

    // reg-staging geometry: thread covers rows row0, row0+8; 8 lanes x 16B per row
    const int row0 = w * 16 + (lane >> 3);
    const int seg  = lane & 7;
    const char* ksrc = kByte + (size_t)row0 * 128  + seg * 16;   // K rows stride 128B
    const char* vsrc = vByte + (size_t)row0 * 2048 + seg * 16;   // V^T rows stride 2048B
    const int swzo = (seg * 16) ^ ((row0 & 7) << 4);             // same for row0 and row0+8
    unsigned short* kw0 = (unsigned short*)((char*)&Ks[row0][0] + swzo);
    unsigned short* kw1 = (unsigned short*)((char*)&Ks[row0 + 8][0] + swzo);
    unsigned short* vw0 = (unsigned short*)((char*)&Vs[row0][0] + swzo);
    unsigned short* vw1 = (unsigned short*)((char*)&Vs[row0 + 8][0] + swzo);

    ushort8 kreg[2], vreg[2];
    kreg[0] = *(const ushort8*)(ksrc);
    kreg[1] = *(const ushort8*)(ksrc + 1024);
    vreg[0] = *(const ushort8*)(vsrc);
    vreg[1] = *(const ushort8*)(vsrc + 16384);

    floatx4 zero4 = {0.f, 0.f, 0.f, 0.f};
    floatx4 accO[4] = {zero4, zero4, zero4, zero4};
    floatx4 accL = zero4;
    bf16x8 ones8;
    #pragma unroll
    for (int j = 0; j < 8; ++j) ones8[j] = (__bf16)1.0f;

    for (int kt = 0; kt < 16; ++kt) {
        __syncthreads();                      // previous tile fully consumed
        *(ushort8*)kw0 = kreg[0];
        *(ushort8*)kw1 = kreg[1];
        *(ushort8*)vw0 = vreg[0];
        *(ushort8*)vw1 = vreg[1];
        __syncthreads();                      // tile ready
        if (kt < 15) {                        // T14: issue next-tile loads under compute
            kreg[0] = *(const ushort8*)(ksrc + (size_t)(kt + 1) * 8192);
            kreg[1] = *(const ushort8*)(ksrc + (size_t)(kt + 1) * 8192 + 1024);
            vreg[0] = *(const ushort8*)(vsrc + (size_t)(kt + 1) * 128);
            vreg[1] = *(const ushort8*)(vsrc + (size_t)(kt + 1) * 128 + 16384);
        }

        floatx4 accS[4];
        #pragma unroll
        for (int mt = 0; mt < 4; ++mt) {
            const int kr = mt * 16 + col;
            const char* krow = (const char*)&Ks[kr][0];
            const int rsw = (kr & 7) << 4;
            bf16x8 kf0 = *(const bf16x8*)(krow + ((qd * 16) ^ rsw));
            bf16x8 kf1 = *(const bf16x8*)(krow + ((64 + qd * 16) ^ rsw));
            accS[mt] = __builtin_amdgcn_mfma_f32_16x16x32_bf16(kf0, qf0, zero4, 0, 0, 0);
            accS[mt] = __builtin_amdgcn_mfma_f32_16x16x32_bf16(kf1, qf1, accS[mt], 0, 0, 0);
        }

        #pragma unroll
        for (int mt = 0; mt < 4; ++mt) {
            bf16x4 pv;
            #pragma unroll
            for (int r = 0; r < 4; ++r) pv[r] = (__bf16)EXP2(accS[mt][r]);
            *(bf16x4*)&ps[w][col][mt * 16 + qd * 4] = pv;
        }

        bf16x8 pf0 = *(const bf16x8*)&ps[w][col][qd * 8];
        bf16x8 pf1 = *(const bf16x8*)&ps[w][col][32 + qd * 8];
        accL = __builtin_amdgcn_mfma_f32_16x16x32_bf16(ones8, pf0, accL, 0, 0, 0);
        accL = __builtin_amdgcn_mfma_f32_16x16x32_bf16(ones8, pf1, accL, 0, 0, 0);

        #pragma unroll
        for (int ct = 0; ct < 4; ++ct) {
            const int vr = ct * 16 + col;
            const char* vrow = (const char*)&Vs[vr][0];
            const int rsw = (vr & 7) << 4;
            bf16x8 vf0 = *(const bf16x8*)(vrow + ((qd * 16) ^ rsw));
            bf16x8 vf1 = *(const bf16x8*)(vrow + ((64 + qd * 16) ^ rsw));
            accO[ct] = __builtin_amdgcn_mfma_f32_16x16x32_bf16(vf0, pf0, accO[ct], 0, 0, 0);
            accO[ct] = __builtin_amdgcn_mfma_f32_16x16x32_bf16(vf1, pf1, accO[ct], 0, 0, 0);
        }
    }

    const float inv_l = 1.0f / accL[0];

    // deposit O^T per wave: ps[w][q=col][d]
    #pragma unroll
    for (int ct = 0; ct < 4; ++ct) {
        bf16x4 o;
        #pragma unroll
        for (int r = 0; r < 4; ++r) o[r] = (__bf16)(accO[ct][r] * inv_l);
        *(bf16x4*)&ps[w][col][ct * 16 + qd * 4] = o;
    }
    __syncthreads();
    // gather across wave planes: channel cb+j <- wave j; p = qq*64 + d
    const int cb = h * 64 + qblk * 4;
    #pragma unroll
    for (int i = 0; i < 4; ++i) {
        const int p = i * 256 + t;
        const int qq = p >> 6, dd = p & 63;
        bf16x4 o;
        #pragma unroll
        for (int j = 0; j < 4; ++j) {
            unsigned short u = ps[j][qq][dd];
            o[j] = *(__bf16*)&u;
        }
        *(bf16x4*)&o2tT[((size_t)b * NPOS + p) * ATTND + cb] = o;
    }
}

// ---------------- kernel C: output GEMM, bf16 MFMA + bias + GN stats (round-2 proven) ----------------
__global__ __launch_bounds__(256) void out_mfma(
    const __bf16* __restrict__ a, const __bf16* __restrict__ woT,
    const float* __restrict__ b_out, float* __restrict__ y,
    float* __restrict__ stats)
{
    const int t = threadIdx.x;
    const int w = t >> 6, lane = t & 63;
    const int col = lane & 15, qd = lane >> 4;
    const int wm = w >> 1, wn = w & 1;
    const int m0 = blockIdx.x * 64, d0 = blockIdx.y * 64;
    const int b = blockIdx.x >> 4;

    __shared__ __align__(16) unsigned short As[64][72];
    __shared__ __align__(16) unsigned short Bs[64][72];
    __shared__ float reds[4], redq[4];

    floatx4 zero4 = {0.f, 0.f, 0.f, 0.f};
    floatx4 acc[2][2];
    #pragma unroll
    for (int i = 0; i < 2; ++i)
        #pragma unroll
        for (int j = 0; j < 2; ++j) acc[i][j] = zero4;

    const int lrow = t >> 2, lc = (t & 3) * 16;

    for (int k0 = 0; k0 < ATTND; k0 += 64) {
        __syncthreads();
        *(ushort8*)&As[lrow][lc]     = *(const ushort8*)&a[(size_t)(m0 + lrow) * ATTND + k0 + lc];
        *(ushort8*)&As[lrow][lc + 8] = *(const ushort8*)&a[(size_t)(m0 + lrow) * ATTND + k0 + lc + 8];
        *(ushort8*)&Bs[lrow][lc]     = *(const ushort8*)&woT[(size_t)(d0 + lrow) * ATTND + k0 + lc];
        *(ushort8*)&Bs[lrow][lc + 8] = *(const ushort8*)&woT[(size_t)(d0 + lrow) * ATTND + k0 + lc + 8];
        __syncthreads();
        bf16x8 af0[2], af1[2];
        #pragma unroll
        for (int mt = 0; mt < 2; ++mt) {
            af0[mt] = *(const bf16x8*)&As[wm * 32 + mt * 16 + col][qd * 8];
            af1[mt] = *(const bf16x8*)&As[wm * 32 + mt * 16 + col][32 + qd * 8];
        }
        #pragma unroll
        for (int nt = 0; nt < 2; ++nt) {
            bf16x8 bf0 = *(const bf16x8*)&Bs[wn * 32 + nt * 16 + col][qd * 8];
            bf16x8 bf1 = *(const bf16x8*)&Bs[wn * 32 + nt * 16 + col][32 + qd * 8];
            #pragma unroll
            for (int mt = 0; mt < 2; ++mt) {
                acc[mt][nt] = __builtin_amdgcn_mfma_f32_16x16x32_bf16(af0[mt], bf0, acc[mt][nt], 0, 0, 0);
                acc[mt][nt] = __builtin_amdgcn_mfma_f32_16x16x32_bf16(af1[mt], bf1, acc[mt][nt], 0, 0, 0);
            }
        }
    }

    float bias_n[2];
    #pragma unroll
    for (int nt = 0; nt < 2; ++nt) bias_n[nt] = b_out[d0 + wn * 32 + nt * 16 + col];

    float bsum = 0.0f, bsq = 0.0f;
    #pragma unroll
    for (int mt = 0; mt < 2; ++mt) {
        #pragma unroll
        for (int r = 0; r < 4; ++r) {
            const int m = m0 + wm * 32 + mt * 16 + qd * 4 + r;
            const int p = m & 1023;
            #pragma unroll
            for (int nt = 0; nt < 2; ++nt) {
                const int d = d0 + wn * 32 + nt * 16 + col;
                const float v = acc[mt][nt][r] + bias_n[nt];
                y[((size_t)b * NPOS + p) * COUT + d] = v;
                bsum += v;
                bsq  += v * v;
            }
        }
    }
    #pragma unroll
    for (int off = 1; off < 64; off <<= 1) {
        bsum += __shfl_xor(bsum, off);
        bsq  += __shfl_xor(bsq, off);
    }
    if (lane == 0) { reds[w] = bsum; redq[w] = bsq; }
    __syncthreads();
    if (t == 0) {
        atomicAdd(&stats[b * 16],       reds[0] + reds[1] + reds[2] + reds[3]);
        atomicAdd(&stats[128 + b * 16], redq[0] + redq[1] + redq[2] + redq[3]);
    }
}

// ---------------- kernel D: GroupNorm finalize ----------------
__global__ __launch_bounds__(256) void gn_finalize(
    float* __restrict__ y, const float* __restrict__ stats,
    const float* __restrict__ gamma, const float* __restrict__ beta)
{
    const int idx = blockIdx.x * 256 + threadIdx.x;
    const int e = idx * 4;
    const int b_ = e >> 18;
    const int d = e & (COUT - 1);
    const float invn = 1.0f / (float)(NPOS * COUT);
    const float mean = stats[b_ * 16] * invn;
    const float var  = stats[128 + b_ * 16] * invn - mean * mean;
    const float rsig = rsqrtf(var + GN_EPS);
    float4 vv = *(float4*)&y[e];
    const float4 g  = *(const float4*)&gamma[d];
    const float4 bt = *(const float4*)&beta[d];
    vv.x = (vv.x - mean) * rsig * g.x + bt.x;
    vv.y = (vv.y - mean) * rsig * g.y + bt.y;
    vv.z = (vv.z - mean) * rsig * g.z + bt.z;
    vv.w = (vv.w - mean) * rsig * g.w + bt.w;
    *(float4*)&y[e] = vv;
}

extern "C" void kernel_launch(void* const* d_in, const int* in_sizes, int n_in,
                              void* d_out, int out_size, void* d_ws, size_t ws_size,
                              hipStream_t stream)
{
    const float* x     = (const float*)d_in[0];
    const float* w_qkv = (const float*)d_in[1];
    const float* w_out = (const float*)d_in[2];
    const float* b_out = (const float*)d_in[3];
    const float* gamma = (const float*)d_in[4];
    const float* beta  = (const float*)d_in[5];
    float* out = (float*)d_out;
    char* ws = (char*)d_ws;

    unsigned short* xb  = (unsigned short*)(ws + OFF_XB);
    unsigned short* wT  = (unsigned short*)(ws + OFF_WT);
    unsigned short* woT = (unsigned short*)(ws + OFF_WOT);
    __bf16* qb  = (__bf16*)(ws + OFF_QB);
    __bf16* kb  = (__bf16*)(ws + OFF_KB);
    __bf16* vT  = (__bf16*)(ws + OFF_VT);
    __bf16* o2tT = (__bf16*)(ws + OFF_O2TT);
    float* stats = (float*)(ws + OFF_ST);

    prep         <<<dim3(384),     256, 0, stream>>>(x, w_qkv, w_out, xb, wT, woT, stats);
    qkv_gemm_mfma<<<dim3(768),     256, 0, stream>>>(xb, (const __bf16*)wT, qb, kb, vT);
    attn_mfma    <<<dim3(1024),    256, 0, stream>>>(qb, kb, vT, o2tT);
    out_mfma     <<<dim3(128, 4),  256, 0, stream>>>(o2tT, (const __bf16*)woT, b_out, out, stats);
    gn_finalize  <<<dim3(2048),    256, 0, stream>>>(out, stats, gamma, beta);
}

// Round 6
// 126.444 us; speedup vs baseline: 1.2420x; 1.0170x over previous
//
#include <hip/hip_runtime.h>
#include <math.h>

#define NPOS   1024
#define CIN    256
#define DQKV   1536
#define ATTND  512
#define HEADS  8
#define DH     64
#define COUT   256
#define NBATCH 8
#define SCALE  0.125f
#define GN_EPS 1e-5f

typedef __attribute__((ext_vector_type(8))) __bf16 bf16x8;
typedef __attribute__((ext_vector_type(4))) __bf16 bf16x4;
typedef __attribute__((ext_vector_type(4))) float floatx4;
typedef __attribute__((ext_vector_type(8))) unsigned short ushort8;

#if __has_builtin(__builtin_amdgcn_exp2f)
#define EXP2(x) __builtin_amdgcn_exp2f(x)
#else
#define EXP2(x) exp2f(x)
#endif

// direct global->LDS DMA, 16B per lane, wave-uniform LDS base
#define GLOAD16(G, L) __builtin_amdgcn_global_load_lds( \
    (const __attribute__((address_space(1))) void*)(G), \
    (__attribute__((address_space(3))) void*)(L), 16, 0, 0)

// ws byte layout:
//   xb    bf16 [8192][256]          @ 0        (x pre-converted to bf16)
//   wT    bf16 [1536][256]          @ 4 MiB    (SCALE*log2e folded into cols<512)
//   woT   bf16 [256][512]           @ 4.75 MiB
//   qb    bf16 [B][H][1024][64]     @ 5 MiB
//   kb    bf16 same                 @ 13 MiB
//   vT    bf16 [B][H][64][1024]     @ 29 MiB
//   o2tT  bf16 [B][1024][512]       @ 45 MiB
//   stats fp32 [256]                @ 53 MiB   sum[b]@b*16, sq[b]@128+b*16
#define OFF_XB   (0ull)
#define OFF_WT   (4ull*1048576)
#define OFF_WOT  (4ull*1048576 + 786432ull)
#define OFF_QB   (5ull*1048576)
#define OFF_KB   (13ull*1048576)
#define OFF_VT   (29ull*1048576)
#define OFF_O2TT (45ull*1048576)
#define OFF_ST   (53ull*1048576)

__device__ inline ushort8 cvt_bf8(float4 a, float4 b) {
    bf16x8 o;
    o[0] = (__bf16)a.x; o[1] = (__bf16)a.y; o[2] = (__bf16)a.z; o[3] = (__bf16)a.w;
    o[4] = (__bf16)b.x; o[5] = (__bf16)b.y; o[6] = (__bf16)b.z; o[7] = (__bf16)b.w;
    return *(ushort8*)&o;
}

// ---------------- prep: weight + x conversions (+ zero stats) ----------------
__global__ __launch_bounds__(256) void prep(
    const float* __restrict__ x,
    const float* __restrict__ w_qkv, const float* __restrict__ w_out,
    unsigned short* __restrict__ xb,
    unsigned short* __restrict__ wT, unsigned short* __restrict__ woT,
    float* __restrict__ stats)
{
    const int bid = blockIdx.x;
    const int t = threadIdx.x;
    __shared__ unsigned short tile[64][68];

    if (bid == 0) stats[t] = 0.0f;

    if (bid >= 128) {   // x -> bf16 (elementwise, any order)
        const size_t base = (size_t)(bid - 128) * 8192 + (size_t)t * 8;
        #pragma unroll
        for (int i = 0; i < 4; ++i) {
            const size_t off = base + (size_t)i * 2048;
            const float4 u = *(const float4*)&x[off];
            const float4 v = *(const float4*)&x[off + 4];
            *(ushort8*)&xb[off] = cvt_bf8(u, v);
        }
        return;
    }

    if (bid < 96) {
        const int n0 = (bid >> 2) * 64, k0 = (bid & 3) * 64;
        #pragma unroll
        for (int p = 0; p < 4; ++p) {
            const int row = p * 16 + (t >> 4);
            const int c = (t & 15) * 4;
            float4 a = *(const float4*)&w_qkv[(size_t)(k0 + row) * DQKV + n0 + c];
            float sv[4] = {a.x, a.y, a.z, a.w};
            #pragma unroll
            for (int j = 0; j < 4; ++j) {
                // fold softmax scale AND log2(e) into Q columns: attn uses raw v_exp_f32 (2^x)
                const float sc = (n0 + c + j) < 512 ? (SCALE * 1.44269504088896f) : 1.0f;
                __bf16 hb = (__bf16)(sv[j] * sc);
                tile[row][c + j] = *(unsigned short*)&hb;
            }
        }
        __syncthreads();
        const int nn = t >> 2;
        const int kc = (t & 3) * 16;
        unsigned short tmp[16];
        #pragma unroll
        for (int j = 0; j < 16; ++j) tmp[j] = tile[kc + j][nn];
        *(ushort8*)&wT[(size_t)(n0 + nn) * 256 + k0 + kc]     = *(ushort8*)&tmp[0];
        *(ushort8*)&wT[(size_t)(n0 + nn) * 256 + k0 + kc + 8] = *(ushort8*)&tmp[8];
        return;
    }

    const int idx = bid - 96;
    const int d0 = (idx & 3) * 64, k0 = (idx >> 2) * 64;
    #pragma unroll
    for (int p = 0; p < 4; ++p) {
        const int row = p * 16 + (t >> 4);
        const int c = (t & 15) * 4;
        float4 a = *(const float4*)&w_out[(size_t)(k0 + row) * COUT + d0 + c];
        float sv[4] = {a.x, a.y, a.z, a.w};
        #pragma unroll
        for (int j = 0; j < 4; ++j) {
            __bf16 hb = (__bf16)sv[j];
            tile[row][c + j] = *(unsigned short*)&hb;
        }
    }
    __syncthreads();
    {
        const int nn = t >> 2;
        const int kc = (t & 3) * 16;
        unsigned short tmp[16];
        #pragma unroll
        for (int j = 0; j < 16; ++j) tmp[j] = tile[kc + j][nn];
        *(ushort8*)&woT[(size_t)(d0 + nn) * 512 + k0 + kc]     = *(ushort8*)&tmp[0];
        *(ushort8*)&woT[(size_t)(d0 + nn) * 512 + k0 + kc + 8] = *(ushort8*)&tmp[8];
    }
}

// ---------------- kernel A: QKV GEMM, bf16 MFMA (bf16 x via prep) ----------------
__global__ __launch_bounds__(256) void qkv_gemm_mfma(
    const unsigned short* __restrict__ xb, const __bf16* __restrict__ wT,
    __bf16* __restrict__ qb, __bf16* __restrict__ kb, __bf16* __restrict__ vT)
{
    const int bid = blockIdx.x;
    // XCD swizzle: each XCD owns 8 consecutive m-tiles x all 12 n-tiles
    const int xcd = bid & 7, local = bid >> 3;           // local 0..95
    const int m0 = (xcd * 8 + (local & 7)) * 128;
    const int n0 = (local >> 3) * 128;

    const int t = threadIdx.x;
    const int w = t >> 6, lane = t & 63;
    const int col = lane & 15, qd = lane >> 4;
    const int wm = w >> 1, wn = w & 1;

    __shared__ __align__(16) unsigned short As[128][40];
    __shared__ __align__(16) unsigned short Bs[128][40];

    floatx4 zero4 = {0.f, 0.f, 0.f, 0.f};
    floatx4 acc[4][4];
    #pragma unroll
    for (int i = 0; i < 4; ++i)
        #pragma unroll
        for (int j = 0; j < 4; ++j) acc[i][j] = zero4;

    const int lrow = t >> 2, lc8 = (t & 3) * 8;

    ushort8 areg[2], breg[2];
    areg[0] = *(const ushort8*)&xb[(size_t)(m0 + lrow) * 256 + lc8];
    areg[1] = *(const ushort8*)&xb[(size_t)(m0 + lrow + 64) * 256 + lc8];
    breg[0] = *(const ushort8*)&wT[(size_t)(n0 + lrow) * 256 + lc8];
    breg[1] = *(const ushort8*)&wT[(size_t)(n0 + lrow + 64) * 256 + lc8];

    for (int kk = 0; kk < 8; ++kk) {
        __syncthreads();
        *(ushort8*)&As[lrow][lc8]      = areg[0];
        *(ushort8*)&As[lrow + 64][lc8] = areg[1];
        *(ushort8*)&Bs[lrow][lc8]      = breg[0];
        *(ushort8*)&Bs[lrow + 64][lc8] = breg[1];
        __syncthreads();
        const int kn = (kk < 7) ? (kk + 1) * 32 : 0;
        areg[0] = *(const ushort8*)&xb[(size_t)(m0 + lrow) * 256 + kn + lc8];
        areg[1] = *(const ushort8*)&xb[(size_t)(m0 + lrow + 64) * 256 + kn + lc8];
        breg[0] = *(const ushort8*)&wT[(size_t)(n0 + lrow) * 256 + kn + lc8];
        breg[1] = *(const ushort8*)&wT[(size_t)(n0 + lrow + 64) * 256 + kn + lc8];

        bf16x8 wf[4];
        #pragma unroll
        for (int ct = 0; ct < 4; ++ct)
            wf[ct] = *(const bf16x8*)&Bs[wn * 64 + ct * 16 + col][qd * 8];
        #pragma unroll
        for (int st = 0; st < 4; ++st) {
            bf16x8 xf = *(const bf16x8*)&As[wm * 64 + st * 16 + col][qd * 8];
            #pragma unroll
            for (int ct = 0; ct < 4; ++ct)
                acc[ct][st] = __builtin_amdgcn_mfma_f32_16x16x32_bf16(wf[ct], xf, acc[ct][st], 0, 0, 0);
        }
    }

    #pragma unroll
    for (int ct = 0; ct < 4; ++ct) {
        const int cbase = n0 + wn * 64 + ct * 16;
        const int sect = cbase >> 9;
        const int hh = (cbase >> 6) & 7;
        const int dd = (cbase & 63) + qd * 4;
        if (sect < 2) {
            __bf16* base = (sect == 0) ? qb : kb;
            #pragma unroll
            for (int st = 0; st < 4; ++st) {
                const int m = m0 + wm * 64 + st * 16 + col;
                const int b_ = m >> 10, n = m & 1023;
                bf16x4 o;
                #pragma unroll
                for (int r = 0; r < 4; ++r) o[r] = (__bf16)acc[ct][st][r];
                *(bf16x4*)&base[(((size_t)b_ * HEADS + hh) * NPOS + n) * DH + dd] = o;
            }
        } else {
            #pragma unroll
            for (int st = 0; st < 4; ++st) {
                const int m = m0 + wm * 64 + st * 16 + col;
                const int b_ = m >> 10, n = m & 1023;
                const size_t rowbase = ((size_t)(b_ * HEADS + hh) * DH + dd) * NPOS + n;
                #pragma unroll
                for (int r = 0; r < 4; ++r)
                    vT[rowbase + (size_t)r * NPOS] = (__bf16)acc[ct][st][r];
            }
        }
    }
}

// ---------------- kernel B: flash attention (round-2 proven structure), TQ=128, 3 blocks/CU ----------------
__global__ __launch_bounds__(256, 3) void attn_mfma(
    const __bf16* __restrict__ qg, const __bf16* __restrict__ kg,
    const __bf16* __restrict__ vTg, __bf16* __restrict__ o2tT)
{
    const int bid = blockIdx.x;
    // XCD swizzle: all 8 qblks of one (b,h) co-located per XCD
    const int rid = (bid & 7) * 64 + (bid >> 3);
    const int qblk = rid & 7, h = (rid >> 3) & 7, b = rid >> 6;
    const int bh = b * HEADS + h;
    const int t = threadIdx.x;
    const int w = t >> 6, lane = t & 63;
    const int col = lane & 15;
    const int qd = lane >> 4;

    __shared__ __align__(16) unsigned short Kbuf[2][64][64];   // K[n][d], XOR-swizzled rows
    __shared__ __align__(16) unsigned short Vbuf[2][64][64];   // V^T[d][n], XOR-swizzled rows
    __shared__ __align__(16) unsigned short ps[4][32][68];     // P round-trip; reused as obuf[16][8][68]

    // Q fragments held in registers for the whole block
    bf16x8 qf0[2], qf1[2];
    #pragma unroll
    for (int s = 0; s < 2; ++s) {
        const __bf16* qptr = qg + ((size_t)bh * NPOS + qblk * 128 + s * 64 + w * 16 + col) * DH;
        qf0[s] = *(const bf16x8*)(qptr + qd * 8);
        qf1[s] = *(const bf16x8*)(qptr + 32 + qd * 8);
    }

    // staging: linear LDS dest (gload_lds writes base + lane*16), INVERSE-swizzled
    // global source; reads apply the same XOR -> involution (rule #21).
    const char* kByte = (const char*)kg  + (size_t)bh * NPOS * DH * 2;
    const char* vByte = (const char*)vTg + (size_t)bh * DH * NPOS * 2;
    const int rsub = lane >> 3;                               // row within 8-row stripe
    const int csw  = ((lane & 7) * 16) ^ (rsub << 4);         // pre-swizzled byte-in-row
    const char* ksrc0 = kByte + (size_t)(w * 8 + rsub) * 128  + csw;  // K rows stride 128B
    const char* vsrc0 = vByte + (size_t)(w * 8 + rsub) * 2048 + csw;  // V rows stride 2048B

#define STAGE(B, KT) do {                                                    \
    const char* ks_ = ksrc0 + (size_t)(KT) * 8192;                           \
    const char* vs_ = vsrc0 + (size_t)(KT) * 128;                            \
    GLOAD16(ks_,         &Kbuf[B][0][0] + w * 512);                          \
    GLOAD16(ks_ + 4096,  &Kbuf[B][0][0] + 2048 + w * 512);                   \
    GLOAD16(vs_,         &Vbuf[B][0][0] + w * 512);                          \
    GLOAD16(vs_ + 65536, &Vbuf[B][0][0] + 2048 + w * 512);                   \
} while (0)

    floatx4 zero4 = {0.f, 0.f, 0.f, 0.f};
    floatx4 accO[2][4];
    #pragma unroll
    for (int s = 0; s < 2; ++s)
        #pragma unroll
        for (int i = 0; i < 4; ++i) accO[s][i] = zero4;
    floatx4 accL[2] = {zero4, zero4};          // softmax denominator via ones-MFMA
    bf16x8 ones8;
    #pragma unroll
    for (int j = 0; j < 8; ++j) ones8[j] = (__bf16)1.0f;

    const int swzc = (col & 7) << 4;
    const int offF0 = (qd * 16) ^ swzc;        // k/d-halves 0..31
    const int offF1 = (64 + qd * 16) ^ swzc;   // halves 32..63

    STAGE(0, 0);
    __syncthreads();                           // drains vmcnt -> tile 0 ready

    int cur = 0;
    for (int kt = 0; kt < 16; ++kt) {
        if (kt < 15) STAGE(cur ^ 1, kt + 1);   // loads fly under this tile's compute

        __builtin_amdgcn_s_setprio(1);
        floatx4 accS[2][4];
        #pragma unroll
        for (int mt = 0; mt < 4; ++mt) {
            const char* krow = (const char*)&Kbuf[cur][mt * 16 + col][0];
            bf16x8 kf0 = *(const bf16x8*)(krow + offF0);
            bf16x8 kf1 = *(const bf16x8*)(krow + offF1);
            #pragma unroll
            for (int s = 0; s < 2; ++s) {
                accS[s][mt] = __builtin_amdgcn_mfma_f32_16x16x32_bf16(kf0, qf0[s], zero4, 0, 0, 0);
                accS[s][mt] = __builtin_amdgcn_mfma_f32_16x16x32_bf16(kf1, qf1[s], accS[s][mt], 0, 0, 0);
            }
        }

        // P = 2^S (log2e pre-folded), straight to bf16, no denominator VALU adds
        #pragma unroll
        for (int s = 0; s < 2; ++s)
            #pragma unroll
            for (int mt = 0; mt < 4; ++mt) {
                bf16x4 pv;
                #pragma unroll
                for (int r = 0; r < 4; ++r) pv[r] = (__bf16)EXP2(accS[s][mt][r]);
                *(bf16x4*)&ps[w][s * 16 + col][mt * 16 + qd * 4] = pv;
            }

        bf16x8 pf0[2], pf1[2];
        #pragma unroll
        for (int s = 0; s < 2; ++s) {
            pf0[s] = *(const bf16x8*)&ps[w][s * 16 + col][qd * 8];
            pf1[s] = *(const bf16x8*)&ps[w][s * 16 + col][32 + qd * 8];
            // denominator: ones^T . P accumulated over all tiles (every row of D
            // holds the full column sum -> no end-of-loop shuffles)
            accL[s] = __builtin_amdgcn_mfma_f32_16x16x32_bf16(ones8, pf0[s], accL[s], 0, 0, 0);
            accL[s] = __builtin_amdgcn_mfma_f32_16x16x32_bf16(ones8, pf1[s], accL[s], 0, 0, 0);
        }

        #pragma unroll
        for (int ct = 0; ct < 4; ++ct) {
            const char* vrow = (const char*)&Vbuf[cur][ct * 16 + col][0];
            bf16x8 vf0 = *(const bf16x8*)(vrow + offF0);
            bf16x8 vf1 = *(const bf16x8*)(vrow + offF1);
            #pragma unroll
            for (int s = 0; s < 2; ++s) {
                accO[s][ct] = __builtin_amdgcn_mfma_f32_16x16x32_bf16(vf0, pf0[s], accO[s][ct], 0, 0, 0);
                accO[s][ct] = __builtin_amdgcn_mfma_f32_16x16x32_bf16(vf1, pf1[s], accO[s][ct], 0, 0, 0);
            }
        }
        __builtin_amdgcn_s_setprio(0);
        __syncthreads();                       // drains next-tile loads + frees cur buffer
        cur ^= 1;
    }
#undef STAGE

    float inv_l[2];
    #pragma unroll
    for (int s = 0; s < 2; ++s) inv_l[s] = 1.0f / accL[s][0];

    unsigned short (*obuf)[8][68] = (unsigned short (*)[8][68])ps;
    __syncthreads();
    #pragma unroll
    for (int s = 0; s < 2; ++s)
        #pragma unroll
        for (int ct = 0; ct < 4; ++ct) {
            bf16x4 o;
            #pragma unroll
            for (int r = 0; r < 4; ++r) o[r] = (__bf16)(accO[s][ct][r] * inv_l[s]);
            *(bf16x4*)&obuf[col][s * 4 + w][ct * 16 + qd * 4] = o;
        }
    __syncthreads();
    const int chbase = h * 64 + qblk * 8;
    #pragma unroll
    for (int i = 0; i < 4; ++i) {
        const int p = i * 256 + t;
        const int pc = p >> 6, cc = p & 63;
        bf16x8 o;
        #pragma unroll
        for (int j = 0; j < 8; ++j) {
            unsigned short u = obuf[pc][j][cc];
            o[j] = *(__bf16*)&u;
        }
        *(bf16x8*)&o2tT[((size_t)b * NPOS + p) * ATTND + chbase] = o;
    }
}

// ---------------- kernel C: output GEMM, bf16 MFMA + bias + GN stats (round-2 proven) ----------------
__global__ __launch_bounds__(256) void out_mfma(
    const __bf16* __restrict__ a, const __bf16* __restrict__ woT,
    const float* __restrict__ b_out, float* __restrict__ y,
    float* __restrict__ stats)
{
    const int t = threadIdx.x;
    const int w = t >> 6, lane = t & 63;
    const int col = lane & 15, qd = lane >> 4;
    const int wm = w >> 1, wn = w & 1;
    const int m0 = blockIdx.x * 64, d0 = blockIdx.y * 64;
    const int b = blockIdx.x >> 4;

    __shared__ __align__(16) unsigned short As[64][72];
    __shared__ __align__(16) unsigned short Bs[64][72];
    __shared__ float reds[4], redq[4];

    floatx4 zero4 = {0.f, 0.f, 0.f, 0.f};
    floatx4 acc[2][2];
    #pragma unroll
    for (int i = 0; i < 2; ++i)
        #pragma unroll
        for (int j = 0; j < 2; ++j) acc[i][j] = zero4;

    const int lrow = t >> 2, lc = (t & 3) * 16;

    for (int k0 = 0; k0 < ATTND; k0 += 64) {
        __syncthreads();
        *(ushort8*)&As[lrow][lc]     = *(const ushort8*)&a[(size_t)(m0 + lrow) * ATTND + k0 + lc];
        *(ushort8*)&As[lrow][lc + 8] = *(const ushort8*)&a[(size_t)(m0 + lrow) * ATTND + k0 + lc + 8];
        *(ushort8*)&Bs[lrow][lc]     = *(const ushort8*)&woT[(size_t)(d0 + lrow) * ATTND + k0 + lc];
        *(ushort8*)&Bs[lrow][lc + 8] = *(const ushort8*)&woT[(size_t)(d0 + lrow) * ATTND + k0 + lc + 8];
        __syncthreads();
        bf16x8 af0[2], af1[2];
        #pragma unroll
        for (int mt = 0; mt < 2; ++mt) {
            af0[mt] = *(const bf16x8*)&As[wm * 32 + mt * 16 + col][qd * 8];
            af1[mt] = *(const bf16x8*)&As[wm * 32 + mt * 16 + col][32 + qd * 8];
        }
        #pragma unroll
        for (int nt = 0; nt < 2; ++nt) {
            bf16x8 bf0 = *(const bf16x8*)&Bs[wn * 32 + nt * 16 + col][qd * 8];
            bf16x8 bf1 = *(const bf16x8*)&Bs[wn * 32 + nt * 16 + col][32 + qd * 8];
            #pragma unroll
            for (int mt = 0; mt < 2; ++mt) {
                acc[mt][nt] = __builtin_amdgcn_mfma_f32_16x16x32_bf16(af0[mt], bf0, acc[mt][nt], 0, 0, 0);
                acc[mt][nt] = __builtin_amdgcn_mfma_f32_16x16x32_bf16(af1[mt], bf1, acc[mt][nt], 0, 0, 0);
            }
        }
    }

    float bias_n[2];
    #pragma unroll
    for (int nt = 0; nt < 2; ++nt) bias_n[nt] = b_out[d0 + wn * 32 + nt * 16 + col];

    float bsum = 0.0f, bsq = 0.0f;
    #pragma unroll
    for (int mt = 0; mt < 2; ++mt) {
        #pragma unroll
        for (int r = 0; r < 4; ++r) {
            const int m = m0 + wm * 32 + mt * 16 + qd * 4 + r;
            const int p = m & 1023;
            #pragma unroll
            for (int nt = 0; nt < 2; ++nt) {
                const int d = d0 + wn * 32 + nt * 16 + col;
                const float v = acc[mt][nt][r] + bias_n[nt];
                y[((size_t)b * NPOS + p) * COUT + d] = v;
                bsum += v;
                bsq  += v * v;
            }
        }
    }
    #pragma unroll
    for (int off = 1; off < 64; off <<= 1) {
        bsum += __shfl_xor(bsum, off);
        bsq  += __shfl_xor(bsq, off);
    }
    if (lane == 0) { reds[w] = bsum; redq[w] = bsq; }
    __syncthreads();
    if (t == 0) {
        atomicAdd(&stats[b * 16],       reds[0] + reds[1] + reds[2] + reds[3]);
        atomicAdd(&stats[128 + b * 16], redq[0] + redq[1] + redq[2] + redq[3]);
    }
}

// ---------------- kernel D: GroupNorm finalize ----------------
__global__ __launch_bounds__(256) void gn_finalize(
    float* __restrict__ y, const float* __restrict__ stats,
    const float* __restrict__ gamma, const float* __restrict__ beta)
{
    const int idx = blockIdx.x * 256 + threadIdx.x;
    const int e = idx * 4;
    const int b_ = e >> 18;
    const int d = e & (COUT - 1);
    const float invn = 1.0f / (float)(NPOS * COUT);
    const float mean = stats[b_ * 16] * invn;
    const float var  = stats[128 + b_ * 16] * invn - mean * mean;
    const float rsig = rsqrtf(var + GN_EPS);
    float4 vv = *(float4*)&y[e];
    const float4 g  = *(const float4*)&gamma[d];
    const float4 bt = *(const float4*)&beta[d];
    vv.x = (vv.x - mean) * rsig * g.x + bt.x;
    vv.y = (vv.y - mean) * rsig * g.y + bt.y;
    vv.z = (vv.z - mean) * rsig * g.z + bt.z;
    vv.w = (vv.w - mean) * rsig * g.w + bt.w;
    *(float4*)&y[e] = vv;
}

extern "C" void kernel_launch(void* const* d_in, const int* in_sizes, int n_in,
                              void* d_out, int out_size, void* d_ws, size_t ws_size,
                              hipStream_t stream)
{
    const float* x     = (const float*)d_in[0];
    const float* w_qkv = (const float*)d_in[1];
    const float* w_out = (const float*)d_in[2];
    const float* b_out = (const float*)d_in[3];
    const float* gamma = (const float*)d_in[4];
    const float* beta  = (const float*)d_in[5];
    float* out = (float*)d_out;
    char* ws = (char*)d_ws;

    unsigned short* xb  = (unsigned short*)(ws + OFF_XB);
    unsigned short* wT  = (unsigned short*)(ws + OFF_WT);
    unsigned short* woT = (unsigned short*)(ws + OFF_WOT);
    __bf16* qb  = (__bf16*)(ws + OFF_QB);
    __bf16* kb  = (__bf16*)(ws + OFF_KB);
    __bf16* vT  = (__bf16*)(ws + OFF_VT);
    __bf16* o2tT = (__bf16*)(ws + OFF_O2TT);
    float* stats = (float*)(ws + OFF_ST);

    prep         <<<dim3(384),     256, 0, stream>>>(x, w_qkv, w_out, xb, wT, woT, stats);
    qkv_gemm_mfma<<<dim3(768),     256, 0, stream>>>(xb, (const __bf16*)wT, qb, kb, vT);
    attn_mfma    <<<dim3(512),     256, 0, stream>>>(qb, kb, vT, o2tT);
    out_mfma     <<<dim3(128, 4),  256, 0, stream>>>(o2tT, (const __bf16*)woT, b_out, out, stats);
    gn_finalize  <<<dim3(2048),    256, 0, stream>>>(out, stats, gamma, beta);
}

// Round 8
// 125.845 us; speedup vs baseline: 1.2479x; 1.0048x over previous
//
#include <hip/hip_runtime.h>
#include <math.h>

#define NPOS   1024
#define CIN    256
#define DQKV   1536
#define ATTND  512
#define HEADS  8
#define DH     64
#define COUT   256
#define NBATCH 8
#define SCALE  0.125f
#define GN_EPS 1e-5f

typedef __attribute__((ext_vector_type(8))) __bf16 bf16x8;
typedef __attribute__((ext_vector_type(4))) __bf16 bf16x4;
typedef __attribute__((ext_vector_type(4))) float floatx4;
typedef __attribute__((ext_vector_type(8))) unsigned short ushort8;

#if __has_builtin(__builtin_amdgcn_exp2f)
#define EXP2(x) __builtin_amdgcn_exp2f(x)
#else
#define EXP2(x) exp2f(x)
#endif

// direct global->LDS DMA, 16B per lane, wave-uniform LDS base
#define GLOAD16(G, L) __builtin_amdgcn_global_load_lds( \
    (const __attribute__((address_space(1))) void*)(G), \
    (__attribute__((address_space(3))) void*)(L), 16, 0, 0)

// ws byte layout:
//   xb    bf16 [8192][256]          @ 0        (x pre-converted to bf16)
//   wT    bf16 [1536][256]          @ 4 MiB    (SCALE*log2e folded into cols<512)
//   woT   bf16 [256][512]           @ 4.75 MiB
//   qb    bf16 [B][H][1024][64]     @ 5 MiB
//   kb    bf16 same                 @ 13 MiB
//   vT    bf16 [B][H][64][1024]     @ 29 MiB
//   o2tT  bf16 [B][1024][512]       @ 45 MiB
//   stats fp32 [256]                @ 53 MiB   sum[b]@b*16, sq[b]@128+b*16
#define OFF_XB   (0ull)
#define OFF_WT   (4ull*1048576)
#define OFF_WOT  (4ull*1048576 + 786432ull)
#define OFF_QB   (5ull*1048576)
#define OFF_KB   (13ull*1048576)
#define OFF_VT   (29ull*1048576)
#define OFF_O2TT (45ull*1048576)
#define OFF_ST   (53ull*1048576)

__device__ inline ushort8 cvt_bf8(float4 a, float4 b) {
    bf16x8 o;
    o[0] = (__bf16)a.x; o[1] = (__bf16)a.y; o[2] = (__bf16)a.z; o[3] = (__bf16)a.w;
    o[4] = (__bf16)b.x; o[5] = (__bf16)b.y; o[6] = (__bf16)b.z; o[7] = (__bf16)b.w;
    return *(ushort8*)&o;
}

// ---------------- prep: weight + x conversions (+ zero stats) ----------------
__global__ __launch_bounds__(256) void prep(
    const float* __restrict__ x,
    const float* __restrict__ w_qkv, const float* __restrict__ w_out,
    unsigned short* __restrict__ xb,
    unsigned short* __restrict__ wT, unsigned short* __restrict__ woT,
    float* __restrict__ stats)
{
    const int bid = blockIdx.x;
    const int t = threadIdx.x;
    __shared__ unsigned short tile[64][68];

    if (bid == 0) stats[t] = 0.0f;

    if (bid >= 128) {   // x -> bf16 (elementwise, any order)
        const size_t base = (size_t)(bid - 128) * 8192 + (size_t)t * 8;
        #pragma unroll
        for (int i = 0; i < 4; ++i) {
            const size_t off = base + (size_t)i * 2048;
            const float4 u = *(const float4*)&x[off];
            const float4 v = *(const float4*)&x[off + 4];
            *(ushort8*)&xb[off] = cvt_bf8(u, v);
        }
        return;
    }

    if (bid < 96) {
        const int n0 = (bid >> 2) * 64, k0 = (bid & 3) * 64;
        #pragma unroll
        for (int p = 0; p < 4; ++p) {
            const int row = p * 16 + (t >> 4);
            const int c = (t & 15) * 4;
            float4 a = *(const float4*)&w_qkv[(size_t)(k0 + row) * DQKV + n0 + c];
            float sv[4] = {a.x, a.y, a.z, a.w};
            #pragma unroll
            for (int j = 0; j < 4; ++j) {
                // fold softmax scale AND log2(e) into Q columns: attn uses raw v_exp_f32 (2^x)
                const float sc = (n0 + c + j) < 512 ? (SCALE * 1.44269504088896f) : 1.0f;
                __bf16 hb = (__bf16)(sv[j] * sc);
                tile[row][c + j] = *(unsigned short*)&hb;
            }
        }
        __syncthreads();
        const int nn = t >> 2;
        const int kc = (t & 3) * 16;
        unsigned short tmp[16];
        #pragma unroll
        for (int j = 0; j < 16; ++j) tmp[j] = tile[kc + j][nn];
        *(ushort8*)&wT[(size_t)(n0 + nn) * 256 + k0 + kc]     = *(ushort8*)&tmp[0];
        *(ushort8*)&wT[(size_t)(n0 + nn) * 256 + k0 + kc + 8] = *(ushort8*)&tmp[8];
        return;
    }

    const int idx = bid - 96;
    const int d0 = (idx & 3) * 64, k0 = (idx >> 2) * 64;
    #pragma unroll
    for (int p = 0; p < 4; ++p) {
        const int row = p * 16 + (t >> 4);
        const int c = (t & 15) * 4;
        float4 a = *(const float4*)&w_out[(size_t)(k0 + row) * COUT + d0 + c];
        float sv[4] = {a.x, a.y, a.z, a.w};
        #pragma unroll
        for (int j = 0; j < 4; ++j) {
            __bf16 hb = (__bf16)sv[j];
            tile[row][c + j] = *(unsigned short*)&hb;
        }
    }
    __syncthreads();
    {
        const int nn = t >> 2;
        const int kc = (t & 3) * 16;
        unsigned short tmp[16];
        #pragma unroll
        for (int j = 0; j < 16; ++j) tmp[j] = tile[kc + j][nn];
        *(ushort8*)&woT[(size_t)(d0 + nn) * 512 + k0 + kc]     = *(ushort8*)&tmp[0];
        *(ushort8*)&woT[(size_t)(d0 + nn) * 512 + k0 + kc + 8] = *(ushort8*)&tmp[8];
    }
}

// ---------------- kernel A: QKV GEMM, bf16 MFMA (bf16 x via prep) ----------------
__global__ __launch_bounds__(256) void qkv_gemm_mfma(
    const unsigned short* __restrict__ xb, const __bf16* __restrict__ wT,
    __bf16* __restrict__ qb, __bf16* __restrict__ kb, __bf16* __restrict__ vT)
{
    const int bid = blockIdx.x;
    // XCD swizzle: each XCD owns 8 consecutive m-tiles x all 12 n-tiles
    const int xcd = bid & 7, local = bid >> 3;           // local 0..95
    const int m0 = (xcd * 8 + (local & 7)) * 128;
    const int n0 = (local >> 3) * 128;

    const int t = threadIdx.x;
    const int w = t >> 6, lane = t & 63;
    const int col = lane & 15, qd = lane >> 4;
    const int wm = w >> 1, wn = w & 1;

    __shared__ __align__(16) unsigned short As[128][40];
    __shared__ __align__(16) unsigned short Bs[128][40];

    floatx4 zero4 = {0.f, 0.f, 0.f, 0.f};
    floatx4 acc[4][4];
    #pragma unroll
    for (int i = 0; i < 4; ++i)
        #pragma unroll
        for (int j = 0; j < 4; ++j) acc[i][j] = zero4;

    const int lrow = t >> 2, lc8 = (t & 3) * 8;

    ushort8 areg[2], breg[2];
    areg[0] = *(const ushort8*)&xb[(size_t)(m0 + lrow) * 256 + lc8];
    areg[1] = *(const ushort8*)&xb[(size_t)(m0 + lrow + 64) * 256 + lc8];
    breg[0] = *(const ushort8*)&wT[(size_t)(n0 + lrow) * 256 + lc8];
    breg[1] = *(const ushort8*)&wT[(size_t)(n0 + lrow + 64) * 256 + lc8];

    for (int kk = 0; kk < 8; ++kk) {
        __syncthreads();
        *(ushort8*)&As[lrow][lc8]      = areg[0];
        *(ushort8*)&As[lrow + 64][lc8] = areg[1];
        *(ushort8*)&Bs[lrow][lc8]      = breg[0];
        *(ushort8*)&Bs[lrow + 64][lc8] = breg[1];
        __syncthreads();
        const int kn = (kk < 7) ? (kk + 1) * 32 : 0;
        areg[0] = *(const ushort8*)&xb[(size_t)(m0 + lrow) * 256 + kn + lc8];
        areg[1] = *(const ushort8*)&xb[(size_t)(m0 + lrow + 64) * 256 + kn + lc8];
        breg[0] = *(const ushort8*)&wT[(size_t)(n0 + lrow) * 256 + kn + lc8];
        breg[1] = *(const ushort8*)&wT[(size_t)(n0 + lrow + 64) * 256 + kn + lc8];

        bf16x8 wf[4];
        #pragma unroll
        for (int ct = 0; ct < 4; ++ct)
            wf[ct] = *(const bf16x8*)&Bs[wn * 64 + ct * 16 + col][qd * 8];
        #pragma unroll
        for (int st = 0; st < 4; ++st) {
            bf16x8 xf = *(const bf16x8*)&As[wm * 64 + st * 16 + col][qd * 8];
            #pragma unroll
            for (int ct = 0; ct < 4; ++ct)
                acc[ct][st] = __builtin_amdgcn_mfma_f32_16x16x32_bf16(wf[ct], xf, acc[ct][st], 0, 0, 0);
        }
    }

    #pragma unroll
    for (int ct = 0; ct < 4; ++ct) {
        const int cbase = n0 + wn * 64 + ct * 16;
        const int sect = cbase >> 9;
        const int hh = (cbase >> 6) & 7;
        const int dd = (cbase & 63) + qd * 4;
        if (sect < 2) {
            __bf16* base = (sect == 0) ? qb : kb;
            #pragma unroll
            for (int st = 0; st < 4; ++st) {
                const int m = m0 + wm * 64 + st * 16 + col;
                const int b_ = m >> 10, n = m & 1023;
                bf16x4 o;
                #pragma unroll
                for (int r = 0; r < 4; ++r) o[r] = (__bf16)acc[ct][st][r];
                *(bf16x4*)&base[(((size_t)b_ * HEADS + hh) * NPOS + n) * DH + dd] = o;
            }
        } else {
            #pragma unroll
            for (int st = 0; st < 4; ++st) {
                const int m = m0 + wm * 64 + st * 16 + col;
                const int b_ = m >> 10, n = m & 1023;
                const size_t rowbase = ((size_t)(b_ * HEADS + hh) * DH + dd) * NPOS + n;
                #pragma unroll
                for (int r = 0; r < 4; ++r)
                    vT[rowbase + (size_t)r * NPOS] = (__bf16)acc[ct][st][r];
            }
        }
    }
}

// ---------------- kernel B: flash attention (round-2 exact, 124.3 us proven) ----------------
__global__ __launch_bounds__(256, 2) void attn_mfma(
    const __bf16* __restrict__ qg, const __bf16* __restrict__ kg,
    const __bf16* __restrict__ vTg, __bf16* __restrict__ o2tT)
{
    const int bid = blockIdx.x;
    // XCD swizzle: all 8 qblks of one (b,h) co-located per XCD
    const int rid = (bid & 7) * 64 + (bid >> 3);
    const int qblk = rid & 7, h = (rid >> 3) & 7, b = rid >> 6;
    const int bh = b * HEADS + h;
    const int t = threadIdx.x;
    const int w = t >> 6, lane = t & 63;
    const int col = lane & 15;
    const int qd = lane >> 4;

    __shared__ __align__(16) unsigned short Kbuf[2][64][64];   // K[n][d], XOR-swizzled rows
    __shared__ __align__(16) unsigned short Vbuf[2][64][64];   // V^T[d][n], XOR-swizzled rows
    __shared__ __align__(16) unsigned short ps[4][32][68];     // P round-trip; reused as obuf[16][8][68]

    // Q fragments held in registers for the whole block
    bf16x8 qf0[2], qf1[2];
    #pragma unroll
    for (int s = 0; s < 2; ++s) {
        const __bf16* qptr = qg + ((size_t)bh * NPOS + qblk * 128 + s * 64 + w * 16 + col) * DH;
        qf0[s] = *(const bf16x8*)(qptr + qd * 8);
        qf1[s] = *(const bf16x8*)(qptr + 32 + qd * 8);
    }

    // staging: linear LDS dest (gload_lds writes base + lane*16), INVERSE-swizzled
    // global source; reads apply the same XOR -> involution (rule #21).
    const char* kByte = (const char*)kg  + (size_t)bh * NPOS * DH * 2;
    const char* vByte = (const char*)vTg + (size_t)bh * DH * NPOS * 2;
    const int rsub = lane >> 3;                               // row within 8-row stripe
    const int csw  = ((lane & 7) * 16) ^ (rsub << 4);         // pre-swizzled byte-in-row
    const char* ksrc0 = kByte + (size_t)(w * 8 + rsub) * 128  + csw;  // K rows stride 128B
    const char* vsrc0 = vByte + (size_t)(w * 8 + rsub) * 2048 + csw;  // V rows stride 2048B

#define STAGE(B, KT) do {                                                    \
    const char* ks_ = ksrc0 + (size_t)(KT) * 8192;                           \
    const char* vs_ = vsrc0 + (size_t)(KT) * 128;                            \
    GLOAD16(ks_,         &Kbuf[B][0][0] + w * 512);                          \
    GLOAD16(ks_ + 4096,  &Kbuf[B][0][0] + 2048 + w * 512);                   \
    GLOAD16(vs_,         &Vbuf[B][0][0] + w * 512);                          \
    GLOAD16(vs_ + 65536, &Vbuf[B][0][0] + 2048 + w * 512);                   \
} while (0)

    floatx4 zero4 = {0.f, 0.f, 0.f, 0.f};
    floatx4 accO[2][4];
    #pragma unroll
    for (int s = 0; s < 2; ++s)
        #pragma unroll
        for (int i = 0; i < 4; ++i) accO[s][i] = zero4;
    floatx4 accL[2] = {zero4, zero4};          // softmax denominator via ones-MFMA
    bf16x8 ones8;
    #pragma unroll
    for (int j = 0; j < 8; ++j) ones8[j] = (__bf16)1.0f;

    const int swzc = (col & 7) << 4;
    const int offF0 = (qd * 16) ^ swzc;        // k/d-halves 0..31
    const int offF1 = (64 + qd * 16) ^ swzc;   // halves 32..63

    STAGE(0, 0);
    __syncthreads();                           // drains vmcnt -> tile 0 ready

    int cur = 0;
    for (int kt = 0; kt < 16; ++kt) {
        if (kt < 15) STAGE(cur ^ 1, kt + 1);   // loads fly under this tile's compute

        floatx4 accS[2][4];
        #pragma unroll
        for (int mt = 0; mt < 4; ++mt) {
            const char* krow = (const char*)&Kbuf[cur][mt * 16 + col][0];
            bf16x8 kf0 = *(const bf16x8*)(krow + offF0);
            bf16x8 kf1 = *(const bf16x8*)(krow + offF1);
            #pragma unroll
            for (int s = 0; s < 2; ++s) {
                accS[s][mt] = __builtin_amdgcn_mfma_f32_16x16x32_bf16(kf0, qf0[s], zero4, 0, 0, 0);
                accS[s][mt] = __builtin_amdgcn_mfma_f32_16x16x32_bf16(kf1, qf1[s], accS[s][mt], 0, 0, 0);
            }
        }

        // P = 2^S (log2e pre-folded), straight to bf16, no denominator VALU adds
        #pragma unroll
        for (int s = 0; s < 2; ++s)
            #pragma unroll
            for (int mt = 0; mt < 4; ++mt) {
                bf16x4 pv;
                #pragma unroll
                for (int r = 0; r < 4; ++r) pv[r] = (__bf16)EXP2(accS[s][mt][r]);
                *(bf16x4*)&ps[w][s * 16 + col][mt * 16 + qd * 4] = pv;
            }

        bf16x8 pf0[2], pf1[2];
        #pragma unroll
        for (int s = 0; s < 2; ++s) {
            pf0[s] = *(const bf16x8*)&ps[w][s * 16 + col][qd * 8];
            pf1[s] = *(const bf16x8*)&ps[w][s * 16 + col][32 + qd * 8];
            // denominator: ones^T . P accumulated over all tiles (every row of D
            // holds the full column sum -> no end-of-loop shuffles)
            accL[s] = __builtin_amdgcn_mfma_f32_16x16x32_bf16(ones8, pf0[s], accL[s], 0, 0, 0);
            accL[s] = __builtin_amdgcn_mfma_f32_16x16x32_bf16(ones8, pf1[s], accL[s], 0, 0, 0);
        }

        #pragma unroll
        for (int ct = 0; ct < 4; ++ct) {
            const char* vrow = (const char*)&Vbuf[cur][ct * 16 + col][0];
            bf16x8 vf0 = *(const bf16x8*)(vrow + offF0);
            bf16x8 vf1 = *(const bf16x8*)(vrow + offF1);
            #pragma unroll
            for (int s = 0; s < 2; ++s) {
                accO[s][ct] = __builtin_amdgcn_mfma_f32_16x16x32_bf16(vf0, pf0[s], accO[s][ct], 0, 0, 0);
                accO[s][ct] = __builtin_amdgcn_mfma_f32_16x16x32_bf16(vf1, pf1[s], accO[s][ct], 0, 0, 0);
            }
        }
        __syncthreads();                       // drains next-tile loads + frees cur buffer
        cur ^= 1;
    }
#undef STAGE

    float inv_l[2];
    #pragma unroll
    for (int s = 0; s < 2; ++s) inv_l[s] = 1.0f / accL[s][0];

    unsigned short (*obuf)[8][68] = (unsigned short (*)[8][68])ps;
    __syncthreads();
    #pragma unroll
    for (int s = 0; s < 2; ++s)
        #pragma unroll
        for (int ct = 0; ct < 4; ++ct) {
            bf16x4 o;
            #pragma unroll
            for (int r = 0; r < 4; ++r) o[r] = (__bf16)(accO[s][ct][r] * inv_l[s]);
            *(bf16x4*)&obuf[col][s * 4 + w][ct * 16 + qd * 4] = o;
        }
    __syncthreads();
    const int chbase = h * 64 + qblk * 8;
    #pragma unroll
    for (int i = 0; i < 4; ++i) {
        const int p = i * 256 + t;
        const int pc = p >> 6, cc = p & 63;
        bf16x8 o;
        #pragma unroll
        for (int j = 0; j < 8; ++j) {
            unsigned short u = obuf[pc][j][cc];
            o[j] = *(__bf16*)&u;
        }
        *(bf16x8*)&o2tT[((size_t)b * NPOS + p) * ATTND + chbase] = o;
    }
}

// ---------------- kernel C: output GEMM, bf16 MFMA + bias + GN stats (round-2 proven) ----------------
__global__ __launch_bounds__(256) void out_mfma(
    const __bf16* __restrict__ a, const __bf16* __restrict__ woT,
    const float* __restrict__ b_out, float* __restrict__ y,
    float* __restrict__ stats)
{
    const int t = threadIdx.x;
    const int w = t >> 6, lane = t & 63;
    const int col = lane & 15, qd = lane >> 4;
    const int wm = w >> 1, wn = w & 1;
    const int m0 = blockIdx.x * 64, d0 = blockIdx.y * 64;
    const int b = blockIdx.x >> 4;

    __shared__ __align__(16) unsigned short As[64][72];
    __shared__ __align__(16) unsigned short Bs[64][72];
    __shared__ float reds[4], redq[4];

    floatx4 zero4 = {0.f, 0.f, 0.f, 0.f};
    floatx4 acc[2][2];
    #pragma unroll
    for (int i = 0; i < 2; ++i)
        #pragma unroll
        for (int j = 0; j < 2; ++j) acc[i][j] = zero4;

    const int lrow = t >> 2, lc = (t & 3) * 16;

    for (int k0 = 0; k0 < ATTND; k0 += 64) {
        __syncthreads();
        *(ushort8*)&As[lrow][lc]     = *(const ushort8*)&a[(size_t)(m0 + lrow) * ATTND + k0 + lc];
        *(ushort8*)&As[lrow][lc + 8] = *(const ushort8*)&a[(size_t)(m0 + lrow) * ATTND + k0 + lc + 8];
        *(ushort8*)&Bs[lrow][lc]     = *(const ushort8*)&woT[(size_t)(d0 + lrow) * ATTND + k0 + lc];
        *(ushort8*)&Bs[lrow][lc + 8] = *(const ushort8*)&woT[(size_t)(d0 + lrow) * ATTND + k0 + lc + 8];
        __syncthreads();
        bf16x8 af0[2], af1[2];
        #pragma unroll
        for (int mt = 0; mt < 2; ++mt) {
            af0[mt] = *(const bf16x8*)&As[wm * 32 + mt * 16 + col][qd * 8];
            af1[mt] = *(const bf16x8*)&As[wm * 32 + mt * 16 + col][32 + qd * 8];
        }
        #pragma unroll
        for (int nt = 0; nt < 2; ++nt) {
            bf16x8 bf0 = *(const bf16x8*)&Bs[wn * 32 + nt * 16 + col][qd * 8];
            bf16x8 bf1 = *(const bf16x8*)&Bs[wn * 32 + nt * 16 + col][32 + qd * 8];
            #pragma unroll
            for (int mt = 0; mt < 2; ++mt) {
                acc[mt][nt] = __builtin_amdgcn_mfma_f32_16x16x32_bf16(af0[mt], bf0, acc[mt][nt], 0, 0, 0);
                acc[mt][nt] = __builtin_amdgcn_mfma_f32_16x16x32_bf16(af1[mt], bf1, acc[mt][nt], 0, 0, 0);
            }
        }
    }

    float bias_n[2];
    #pragma unroll
    for (int nt = 0; nt < 2; ++nt) bias_n[nt] = b_out[d0 + wn * 32 + nt * 16 + col];

    float bsum = 0.0f, bsq = 0.0f;
    #pragma unroll
    for (int mt = 0; mt < 2; ++mt) {
        #pragma unroll
        for (int r = 0; r < 4; ++r) {
            const int m = m0 + wm * 32 + mt * 16 + qd * 4 + r;
            const int p = m & 1023;
            #pragma unroll
            for (int nt = 0; nt < 2; ++nt) {
                const int d = d0 + wn * 32 + nt * 16 + col;
                const float v = acc[mt][nt][r] + bias_n[nt];
                y[((size_t)b * NPOS + p) * COUT + d] = v;
                bsum += v;
                bsq  += v * v;
            }
        }
    }
    #pragma unroll
    for (int off = 1; off < 64; off <<= 1) {
        bsum += __shfl_xor(bsum, off);
        bsq  += __shfl_xor(bsq, off);
    }
    if (lane == 0) { reds[w] = bsum; redq[w] = bsq; }
    __syncthreads();
    if (t == 0) {
        atomicAdd(&stats[b * 16],       reds[0] + reds[1] + reds[2] + reds[3]);
        atomicAdd(&stats[128 + b * 16], redq[0] + redq[1] + redq[2] + redq[3]);
    }
}

// ---------------- kernel D: GroupNorm finalize ----------------
__global__ __launch_bounds__(256) void gn_finalize(
    float* __restrict__ y, const float* __restrict__ stats,
    const float* __restrict__ gamma, const float* __restrict__ beta)
{
    const int idx = blockIdx.x * 256 + threadIdx.x;
    const int e = idx * 4;
    const int b_ = e >> 18;
    const int d = e & (COUT - 1);
    const float invn = 1.0f / (float)(NPOS * COUT);
    const float mean = stats[b_ * 16] * invn;
    const float var  = stats[128 + b_ * 16] * invn - mean * mean;
    const float rsig = rsqrtf(var + GN_EPS);
    float4 vv = *(float4*)&y[e];
    const float4 g  = *(const float4*)&gamma[d];
    const float4 bt = *(const float4*)&beta[d];
    vv.x = (vv.x - mean) * rsig * g.x + bt.x;
    vv.y = (vv.y - mean) * rsig * g.y + bt.y;
    vv.z = (vv.z - mean) * rsig * g.z + bt.z;
    vv.w = (vv.w - mean) * rsig * g.w + bt.w;
    *(float4*)&y[e] = vv;
}

extern "C" void kernel_launch(void* const* d_in, const int* in_sizes, int n_in,
                              void* d_out, int out_size, void* d_ws, size_t ws_size,
                              hipStream_t stream)
{
    const float* x     = (const float*)d_in[0];
    const float* w_qkv = (const float*)d_in[1];
    const float* w_out = (const float*)d_in[2];
    const float* b_out = (const float*)d_in[3];
    const float* gamma = (const float*)d_in[4];
    const float* beta  = (const float*)d_in[5];
    float* out = (float*)d_out;
    char* ws = (char*)d_ws;

    unsigned short* xb  = (unsigned short*)(ws + OFF_XB);
    unsigned short* wT  = (unsigned short*)(ws + OFF_WT);
    unsigned short* woT = (unsigned short*)(ws + OFF_WOT);
    __bf16* qb  = (__bf16*)(ws + OFF_QB);
    __bf16* kb  = (__bf16*)(ws + OFF_KB);
    __bf16* vT  = (__bf16*)(ws + OFF_VT);
    __bf16* o2tT = (__bf16*)(ws + OFF_O2TT);
    float* stats = (float*)(ws + OFF_ST);

    prep         <<<dim3(384),     256, 0, stream>>>(x, w_qkv, w_out, xb, wT, woT, stats);
    qkv_gemm_mfma<<<dim3(768),     256, 0, stream>>>(xb, (const __bf16*)wT, qb, kb, vT);
    attn_mfma    <<<dim3(512),     256, 0, stream>>>(qb, kb, vT, o2tT);
    out_mfma     <<<dim3(128, 4),  256, 0, stream>>>(o2tT, (const __bf16*)woT, b_out, out, stats);
    gn_finalize  <<<dim3(2048),    256, 0, stream>>>(out, stats, gamma, beta);
}

// Round 9
// 124.604 us; speedup vs baseline: 1.2604x; 1.0100x over previous
//
#include <hip/hip_runtime.h>
#include <math.h>

#define NPOS   1024
#define CIN    256
#define DQKV   1536
#define ATTND  512
#define HEADS  8
#define DH     64
#define COUT   256
#define NBATCH 8
#define SCALE  0.125f
#define GN_EPS 1e-5f

typedef __attribute__((ext_vector_type(8))) __bf16 bf16x8;
typedef __attribute__((ext_vector_type(4))) __bf16 bf16x4;
typedef __attribute__((ext_vector_type(4))) float floatx4;
typedef __attribute__((ext_vector_type(8))) unsigned short ushort8;

#if __has_builtin(__builtin_amdgcn_exp2f)
#define EXP2(x) __builtin_amdgcn_exp2f(x)
#else
#define EXP2(x) exp2f(x)
#endif

// direct global->LDS DMA, 16B per lane, wave-uniform LDS base
#define GLOAD16(G, L) __builtin_amdgcn_global_load_lds( \
    (const __attribute__((address_space(1))) void*)(G), \
    (__attribute__((address_space(3))) void*)(L), 16, 0, 0)

// ws byte layout:
//   xb    bf16 [8192][256]          @ 0        (x pre-converted to bf16)
//   wT    bf16 [1536][256]          @ 4 MiB    (SCALE*log2e folded into cols<512)
//   woT   bf16 [256][512]           @ 4.75 MiB
//   qb    bf16 [B][H][1024][64]     @ 5 MiB
//   kb    bf16 same                 @ 13 MiB
//   vT    bf16 [B][H][64][1024]     @ 29 MiB
//   o2tT  bf16 [B][1024][512]       @ 45 MiB
//   stats fp32 [256]                @ 53 MiB   sum[b]@b*16, sq[b]@128+b*16
#define OFF_XB   (0ull)
#define OFF_WT   (4ull*1048576)
#define OFF_WOT  (4ull*1048576 + 786432ull)
#define OFF_QB   (5ull*1048576)
#define OFF_KB   (13ull*1048576)
#define OFF_VT   (29ull*1048576)
#define OFF_O2TT (45ull*1048576)
#define OFF_ST   (53ull*1048576)

__device__ inline ushort8 cvt_bf8(float4 a, float4 b) {
    bf16x8 o;
    o[0] = (__bf16)a.x; o[1] = (__bf16)a.y; o[2] = (__bf16)a.z; o[3] = (__bf16)a.w;
    o[4] = (__bf16)b.x; o[5] = (__bf16)b.y; o[6] = (__bf16)b.z; o[7] = (__bf16)b.w;
    return *(ushort8*)&o;
}

// ---------------- prep: weight + x conversions (+ zero stats) ----------------
__global__ __launch_bounds__(256) void prep(
    const float* __restrict__ x,
    const float* __restrict__ w_qkv, const float* __restrict__ w_out,
    unsigned short* __restrict__ xb,
    unsigned short* __restrict__ wT, unsigned short* __restrict__ woT,
    float* __restrict__ stats)
{
    const int bid = blockIdx.x;
    const int t = threadIdx.x;
    __shared__ unsigned short tile[64][68];

    if (bid == 0) stats[t] = 0.0f;

    if (bid >= 128) {   // x -> bf16 (elementwise, any order)
        const size_t base = (size_t)(bid - 128) * 8192 + (size_t)t * 8;
        #pragma unroll
        for (int i = 0; i < 4; ++i) {
            const size_t off = base + (size_t)i * 2048;
            const float4 u = *(const float4*)&x[off];
            const float4 v = *(const float4*)&x[off + 4];
            *(ushort8*)&xb[off] = cvt_bf8(u, v);
        }
        return;
    }

    if (bid < 96) {
        const int n0 = (bid >> 2) * 64, k0 = (bid & 3) * 64;
        #pragma unroll
        for (int p = 0; p < 4; ++p) {
            const int row = p * 16 + (t >> 4);
            const int c = (t & 15) * 4;
            float4 a = *(const float4*)&w_qkv[(size_t)(k0 + row) * DQKV + n0 + c];
            float sv[4] = {a.x, a.y, a.z, a.w};
            #pragma unroll
            for (int j = 0; j < 4; ++j) {
                // fold softmax scale AND log2(e) into Q columns: attn uses raw v_exp_f32 (2^x)
                const float sc = (n0 + c + j) < 512 ? (SCALE * 1.44269504088896f) : 1.0f;
                __bf16 hb = (__bf16)(sv[j] * sc);
                tile[row][c + j] = *(unsigned short*)&hb;
            }
        }
        __syncthreads();
        const int nn = t >> 2;
        const int kc = (t & 3) * 16;
        unsigned short tmp[16];
        #pragma unroll
        for (int j = 0; j < 16; ++j) tmp[j] = tile[kc + j][nn];
        *(ushort8*)&wT[(size_t)(n0 + nn) * 256 + k0 + kc]     = *(ushort8*)&tmp[0];
        *(ushort8*)&wT[(size_t)(n0 + nn) * 256 + k0 + kc + 8] = *(ushort8*)&tmp[8];
        return;
    }

    const int idx = bid - 96;
    const int d0 = (idx & 3) * 64, k0 = (idx >> 2) * 64;
    #pragma unroll
    for (int p = 0; p < 4; ++p) {
        const int row = p * 16 + (t >> 4);
        const int c = (t & 15) * 4;
        float4 a = *(const float4*)&w_out[(size_t)(k0 + row) * COUT + d0 + c];
        float sv[4] = {a.x, a.y, a.z, a.w};
        #pragma unroll
        for (int j = 0; j < 4; ++j) {
            __bf16 hb = (__bf16)sv[j];
            tile[row][c + j] = *(unsigned short*)&hb;
        }
    }
    __syncthreads();
    {
        const int nn = t >> 2;
        const int kc = (t & 3) * 16;
        unsigned short tmp[16];
        #pragma unroll
        for (int j = 0; j < 16; ++j) tmp[j] = tile[kc + j][nn];
        *(ushort8*)&woT[(size_t)(d0 + nn) * 512 + k0 + kc]     = *(ushort8*)&tmp[0];
        *(ushort8*)&woT[(size_t)(d0 + nn) * 512 + k0 + kc + 8] = *(ushort8*)&tmp[8];
    }
}

// ---------------- kernel A: QKV GEMM, gload_lds double-buffered staging ----------------
// LDS tiles [128][32] ushort (64B rows), slot-swizzled: LDS[row][slot] holds source
// k-chunk (slot ^ ((row>>1)&3)). gload_lds dest is linear; source pre-applies the
// inverse (same) XOR; fragment reads apply it again -> involution (rule #21).
__global__ __launch_bounds__(256) void qkv_gemm_mfma(
    const unsigned short* __restrict__ xb, const __bf16* __restrict__ wT,
    __bf16* __restrict__ qb, __bf16* __restrict__ kb, __bf16* __restrict__ vT)
{
    const int bid = blockIdx.x;
    // XCD swizzle: each XCD owns 8 consecutive m-tiles x all 12 n-tiles
    const int xcd = bid & 7, local = bid >> 3;           // local 0..95
    const int m0 = (xcd * 8 + (local & 7)) * 128;
    const int n0 = (local >> 3) * 128;

    const int t = threadIdx.x;
    const int w = t >> 6, lane = t & 63;
    const int col = lane & 15, qd = lane >> 4;
    const int wm = w >> 1, wn = w & 1;

    __shared__ __align__(16) unsigned short As[2][128][32];
    __shared__ __align__(16) unsigned short Bs[2][128][32];

    floatx4 zero4 = {0.f, 0.f, 0.f, 0.f};
    floatx4 acc[4][4];
    #pragma unroll
    for (int i = 0; i < 4; ++i)
        #pragma unroll
        for (int j = 0; j < 4; ++j) acc[i][j] = zero4;

    // staging geometry: wave w covers rows [w*16, w*16+16) and [64+w*16, ...)
    const int arow = lane >> 2;                                   // 0..15
    const int soff = (((lane & 3) ^ ((lane >> 3) & 3)) << 4);     // inverse slot swizzle
    const char* xsrc = (const char*)xb + (size_t)(m0 + w * 16 + arow) * 512 + soff;
    const char* wsrc = (const char*)wT + (size_t)(n0 + w * 16 + arow) * 512 + soff;

#define QSTAGE(B, KK) do {                                            \
    GLOAD16(xsrc + (KK) * 64,             &As[B][w * 16][0]);         \
    GLOAD16(xsrc + 32768 + (KK) * 64,     &As[B][64 + w * 16][0]);    \
    GLOAD16(wsrc + (KK) * 64,             &Bs[B][w * 16][0]);         \
    GLOAD16(wsrc + 32768 + (KK) * 64,     &Bs[B][64 + w * 16][0]);    \
} while (0)

    QSTAGE(0, 0);
    __syncthreads();                       // drains vmcnt -> tile 0 ready

    const int rsw = ((col >> 1) & 3);      // (row>>1)&3 for row = 16*base + col
    const int fro = ((qd ^ rsw) << 4);     // byte offset of logical k-chunk qd

    int cur = 0;
    for (int kk = 0; kk < 8; ++kk) {
        if (kk < 7) QSTAGE(cur ^ 1, kk + 1);   // next-tile loads fly under compute

        bf16x8 wf[4];
        #pragma unroll
        for (int ct = 0; ct < 4; ++ct)
            wf[ct] = *(const bf16x8*)((const char*)&Bs[cur][wn * 64 + ct * 16 + col][0] + fro);
        #pragma unroll
        for (int st = 0; st < 4; ++st) {
            bf16x8 xf = *(const bf16x8*)((const char*)&As[cur][wm * 64 + st * 16 + col][0] + fro);
            #pragma unroll
            for (int ct = 0; ct < 4; ++ct)
                acc[ct][st] = __builtin_amdgcn_mfma_f32_16x16x32_bf16(wf[ct], xf, acc[ct][st], 0, 0, 0);
        }
        __syncthreads();                   // drains next-tile gloads + frees cur
        cur ^= 1;
    }
#undef QSTAGE

    #pragma unroll
    for (int ct = 0; ct < 4; ++ct) {
        const int cbase = n0 + wn * 64 + ct * 16;
        const int sect = cbase >> 9;
        const int hh = (cbase >> 6) & 7;
        const int dd = (cbase & 63) + qd * 4;
        if (sect < 2) {
            __bf16* base = (sect == 0) ? qb : kb;
            #pragma unroll
            for (int st = 0; st < 4; ++st) {
                const int m = m0 + wm * 64 + st * 16 + col;
                const int b_ = m >> 10, n = m & 1023;
                bf16x4 o;
                #pragma unroll
                for (int r = 0; r < 4; ++r) o[r] = (__bf16)acc[ct][st][r];
                *(bf16x4*)&base[(((size_t)b_ * HEADS + hh) * NPOS + n) * DH + dd] = o;
            }
        } else {
            #pragma unroll
            for (int st = 0; st < 4; ++st) {
                const int m = m0 + wm * 64 + st * 16 + col;
                const int b_ = m >> 10, n = m & 1023;
                const size_t rowbase = ((size_t)(b_ * HEADS + hh) * DH + dd) * NPOS + n;
                #pragma unroll
                for (int r = 0; r < 4; ++r)
                    vT[rowbase + (size_t)r * NPOS] = (__bf16)acc[ct][st][r];
            }
        }
    }
}

// ---------------- kernel B: flash attention (round-2 exact, proven) ----------------
__global__ __launch_bounds__(256, 2) void attn_mfma(
    const __bf16* __restrict__ qg, const __bf16* __restrict__ kg,
    const __bf16* __restrict__ vTg, __bf16* __restrict__ o2tT)
{
    const int bid = blockIdx.x;
    // XCD swizzle: all 8 qblks of one (b,h) co-located per XCD
    const int rid = (bid & 7) * 64 + (bid >> 3);
    const int qblk = rid & 7, h = (rid >> 3) & 7, b = rid >> 6;
    const int bh = b * HEADS + h;
    const int t = threadIdx.x;
    const int w = t >> 6, lane = t & 63;
    const int col = lane & 15;
    const int qd = lane >> 4;

    __shared__ __align__(16) unsigned short Kbuf[2][64][64];   // K[n][d], XOR-swizzled rows
    __shared__ __align__(16) unsigned short Vbuf[2][64][64];   // V^T[d][n], XOR-swizzled rows
    __shared__ __align__(16) unsigned short ps[4][32][68];     // P round-trip; reused as obuf[16][8][68]

    // Q fragments held in registers for the whole block
    bf16x8 qf0[2], qf1[2];
    #pragma unroll
    for (int s = 0; s < 2; ++s) {
        const __bf16* qptr = qg + ((size_t)bh * NPOS + qblk * 128 + s * 64 + w * 16 + col) * DH;
        qf0[s] = *(const bf16x8*)(qptr + qd * 8);
        qf1[s] = *(const bf16x8*)(qptr + 32 + qd * 8);
    }

    // staging: linear LDS dest (gload_lds writes base + lane*16), INVERSE-swizzled
    // global source; reads apply the same XOR -> involution (rule #21).
    const char* kByte = (const char*)kg  + (size_t)bh * NPOS * DH * 2;
    const char* vByte = (const char*)vTg + (size_t)bh * DH * NPOS * 2;
    const int rsub = lane >> 3;                               // row within 8-row stripe
    const int csw  = ((lane & 7) * 16) ^ (rsub << 4);         // pre-swizzled byte-in-row
    const char* ksrc0 = kByte + (size_t)(w * 8 + rsub) * 128  + csw;  // K rows stride 128B
    const char* vsrc0 = vByte + (size_t)(w * 8 + rsub) * 2048 + csw;  // V rows stride 2048B

#define STAGE(B, KT) do {                                                    \
    const char* ks_ = ksrc0 + (size_t)(KT) * 8192;                           \
    const char* vs_ = vsrc0 + (size_t)(KT) * 128;                            \
    GLOAD16(ks_,         &Kbuf[B][0][0] + w * 512);                          \
    GLOAD16(ks_ + 4096,  &Kbuf[B][0][0] + 2048 + w * 512);                   \
    GLOAD16(vs_,         &Vbuf[B][0][0] + w * 512);                          \
    GLOAD16(vs_ + 65536, &Vbuf[B][0][0] + 2048 + w * 512);                   \
} while (0)

    floatx4 zero4 = {0.f, 0.f, 0.f, 0.f};
    floatx4 accO[2][4];
    #pragma unroll
    for (int s = 0; s < 2; ++s)
        #pragma unroll
        for (int i = 0; i < 4; ++i) accO[s][i] = zero4;
    floatx4 accL[2] = {zero4, zero4};          // softmax denominator via ones-MFMA
    bf16x8 ones8;
    #pragma unroll
    for (int j = 0; j < 8; ++j) ones8[j] = (__bf16)1.0f;

    const int swzc = (col & 7) << 4;
    const int offF0 = (qd * 16) ^ swzc;        // k/d-halves 0..31
    const int offF1 = (64 + qd * 16) ^ swzc;   // halves 32..63

    STAGE(0, 0);
    __syncthreads();                           // drains vmcnt -> tile 0 ready

    int cur = 0;
    for (int kt = 0; kt < 16; ++kt) {
        if (kt < 15) STAGE(cur ^ 1, kt + 1);   // loads fly under this tile's compute

        floatx4 accS[2][4];
        #pragma unroll
        for (int mt = 0; mt < 4; ++mt) {
            const char* krow = (const char*)&Kbuf[cur][mt * 16 + col][0];
            bf16x8 kf0 = *(const bf16x8*)(krow + offF0);
            bf16x8 kf1 = *(const bf16x8*)(krow + offF1);
            #pragma unroll
            for (int s = 0; s < 2; ++s) {
                accS[s][mt] = __builtin_amdgcn_mfma_f32_16x16x32_bf16(kf0, qf0[s], zero4, 0, 0, 0);
                accS[s][mt] = __builtin_amdgcn_mfma_f32_16x16x32_bf16(kf1, qf1[s], accS[s][mt], 0, 0, 0);
            }
        }

        // P = 2^S (log2e pre-folded), straight to bf16, no denominator VALU adds
        #pragma unroll
        for (int s = 0; s < 2; ++s)
            #pragma unroll
            for (int mt = 0; mt < 4; ++mt) {
                bf16x4 pv;
                #pragma unroll
                for (int r = 0; r < 4; ++r) pv[r] = (__bf16)EXP2(accS[s][mt][r]);
                *(bf16x4*)&ps[w][s * 16 + col][mt * 16 + qd * 4] = pv;
            }

        bf16x8 pf0[2], pf1[2];
        #pragma unroll
        for (int s = 0; s < 2; ++s) {
            pf0[s] = *(const bf16x8*)&ps[w][s * 16 + col][qd * 8];
            pf1[s] = *(const bf16x8*)&ps[w][s * 16 + col][32 + qd * 8];
            // denominator: ones^T . P accumulated over all tiles (every row of D
            // holds the full column sum -> no end-of-loop shuffles)
            accL[s] = __builtin_amdgcn_mfma_f32_16x16x32_bf16(ones8, pf0[s], accL[s], 0, 0, 0);
            accL[s] = __builtin_amdgcn_mfma_f32_16x16x32_bf16(ones8, pf1[s], accL[s], 0, 0, 0);
        }

        #pragma unroll
        for (int ct = 0; ct < 4; ++ct) {
            const char* vrow = (const char*)&Vbuf[cur][ct * 16 + col][0];
            bf16x8 vf0 = *(const bf16x8*)(vrow + offF0);
            bf16x8 vf1 = *(const bf16x8*)(vrow + offF1);
            #pragma unroll
            for (int s = 0; s < 2; ++s) {
                accO[s][ct] = __builtin_amdgcn_mfma_f32_16x16x32_bf16(vf0, pf0[s], accO[s][ct], 0, 0, 0);
                accO[s][ct] = __builtin_amdgcn_mfma_f32_16x16x32_bf16(vf1, pf1[s], accO[s][ct], 0, 0, 0);
            }
        }
        __syncthreads();                       // drains next-tile loads + frees cur buffer
        cur ^= 1;
    }
#undef STAGE

    float inv_l[2];
    #pragma unroll
    for (int s = 0; s < 2; ++s) inv_l[s] = 1.0f / accL[s][0];

    unsigned short (*obuf)[8][68] = (unsigned short (*)[8][68])ps;
    __syncthreads();
    #pragma unroll
    for (int s = 0; s < 2; ++s)
        #pragma unroll
        for (int ct = 0; ct < 4; ++ct) {
            bf16x4 o;
            #pragma unroll
            for (int r = 0; r < 4; ++r) o[r] = (__bf16)(accO[s][ct][r] * inv_l[s]);
            *(bf16x4*)&obuf[col][s * 4 + w][ct * 16 + qd * 4] = o;
        }
    __syncthreads();
    const int chbase = h * 64 + qblk * 8;
    #pragma unroll
    for (int i = 0; i < 4; ++i) {
        const int p = i * 256 + t;
        const int pc = p >> 6, cc = p & 63;
        bf16x8 o;
        #pragma unroll
        for (int j = 0; j < 8; ++j) {
            unsigned short u = obuf[pc][j][cc];
            o[j] = *(__bf16*)&u;
        }
        *(bf16x8*)&o2tT[((size_t)b * NPOS + p) * ATTND + chbase] = o;
    }
}

// ---------------- kernel C: output GEMM + bias + GN stats, XCD-swizzled grid ----------------
__global__ __launch_bounds__(256) void out_mfma(
    const __bf16* __restrict__ a, const __bf16* __restrict__ woT,
    const float* __restrict__ b_out, float* __restrict__ y,
    float* __restrict__ stats)
{
    const int bid = blockIdx.x;
    // XCD swizzle: each XCD owns 16 consecutive m-tiles x all 4 d-tiles
    // -> o2tT panel (1 MB) + woT (256 KB) L2-resident per XCD
    const int xcd = bid & 7, local = bid >> 3;            // local 0..63
    const int m0 = (xcd * 16 + (local & 15)) * 64;
    const int d0 = (local >> 4) * 64;
    const int b = xcd;

    const int t = threadIdx.x;
    const int w = t >> 6, lane = t & 63;
    const int col = lane & 15, qd = lane >> 4;
    const int wm = w >> 1, wn = w & 1;

    __shared__ __align__(16) unsigned short As[64][72];
    __shared__ __align__(16) unsigned short Bs[64][72];
    __shared__ float reds[4], redq[4];

    floatx4 zero4 = {0.f, 0.f, 0.f, 0.f};
    floatx4 acc[2][2];
    #pragma unroll
    for (int i = 0; i < 2; ++i)
        #pragma unroll
        for (int j = 0; j < 2; ++j) acc[i][j] = zero4;

    const int lrow = t >> 2, lc = (t & 3) * 16;

    for (int k0 = 0; k0 < ATTND; k0 += 64) {
        __syncthreads();
        *(ushort8*)&As[lrow][lc]     = *(const ushort8*)&a[(size_t)(m0 + lrow) * ATTND + k0 + lc];
        *(ushort8*)&As[lrow][lc + 8] = *(const ushort8*)&a[(size_t)(m0 + lrow) * ATTND + k0 + lc + 8];
        *(ushort8*)&Bs[lrow][lc]     = *(const ushort8*)&woT[(size_t)(d0 + lrow) * ATTND + k0 + lc];
        *(ushort8*)&Bs[lrow][lc + 8] = *(const ushort8*)&woT[(size_t)(d0 + lrow) * ATTND + k0 + lc + 8];
        __syncthreads();
        bf16x8 af0[2], af1[2];
        #pragma unroll
        for (int mt = 0; mt < 2; ++mt) {
            af0[mt] = *(const bf16x8*)&As[wm * 32 + mt * 16 + col][qd * 8];
            af1[mt] = *(const bf16x8*)&As[wm * 32 + mt * 16 + col][32 + qd * 8];
        }
        #pragma unroll
        for (int nt = 0; nt < 2; ++nt) {
            bf16x8 bf0 = *(const bf16x8*)&Bs[wn * 32 + nt * 16 + col][qd * 8];
            bf16x8 bf1 = *(const bf16x8*)&Bs[wn * 32 + nt * 16 + col][32 + qd * 8];
            #pragma unroll
            for (int mt = 0; mt < 2; ++mt) {
                acc[mt][nt] = __builtin_amdgcn_mfma_f32_16x16x32_bf16(af0[mt], bf0, acc[mt][nt], 0, 0, 0);
                acc[mt][nt] = __builtin_amdgcn_mfma_f32_16x16x32_bf16(af1[mt], bf1, acc[mt][nt], 0, 0, 0);
            }
        }
    }

    float bias_n[2];
    #pragma unroll
    for (int nt = 0; nt < 2; ++nt) bias_n[nt] = b_out[d0 + wn * 32 + nt * 16 + col];

    float bsum = 0.0f, bsq = 0.0f;
    #pragma unroll
    for (int mt = 0; mt < 2; ++mt) {
        #pragma unroll
        for (int r = 0; r < 4; ++r) {
            const int m = m0 + wm * 32 + mt * 16 + qd * 4 + r;
            const int p = m & 1023;
            #pragma unroll
            for (int nt = 0; nt < 2; ++nt) {
                const int d = d0 + wn * 32 + nt * 16 + col;
                const float v = acc[mt][nt][r] + bias_n[nt];
                y[((size_t)b * NPOS + p) * COUT + d] = v;
                bsum += v;
                bsq  += v * v;
            }
        }
    }
    #pragma unroll
    for (int off = 1; off < 64; off <<= 1) {
        bsum += __shfl_xor(bsum, off);
        bsq  += __shfl_xor(bsq, off);
    }
    if (lane == 0) { reds[w] = bsum; redq[w] = bsq; }
    __syncthreads();
    if (t == 0) {
        atomicAdd(&stats[b * 16],       reds[0] + reds[1] + reds[2] + reds[3]);
        atomicAdd(&stats[128 + b * 16], redq[0] + redq[1] + redq[2] + redq[3]);
    }
}

// ---------------- kernel D: GroupNorm finalize ----------------
__global__ __launch_bounds__(256) void gn_finalize(
    float* __restrict__ y, const float* __restrict__ stats,
    const float* __restrict__ gamma, const float* __restrict__ beta)
{
    const int idx = blockIdx.x * 256 + threadIdx.x;
    const int e = idx * 4;
    const int b_ = e >> 18;
    const int d = e & (COUT - 1);
    const float invn = 1.0f / (float)(NPOS * COUT);
    const float mean = stats[b_ * 16] * invn;
    const float var  = stats[128 + b_ * 16] * invn - mean * mean;
    const float rsig = rsqrtf(var + GN_EPS);
    float4 vv = *(float4*)&y[e];
    const float4 g  = *(const float4*)&gamma[d];
    const float4 bt = *(const float4*)&beta[d];
    vv.x = (vv.x - mean) * rsig * g.x + bt.x;
    vv.y = (vv.y - mean) * rsig * g.y + bt.y;
    vv.z = (vv.z - mean) * rsig * g.z + bt.z;
    vv.w = (vv.w - mean) * rsig * g.w + bt.w;
    *(float4*)&y[e] = vv;
}

extern "C" void kernel_launch(void* const* d_in, const int* in_sizes, int n_in,
                              void* d_out, int out_size, void* d_ws, size_t ws_size,
                              hipStream_t stream)
{
    const float* x     = (const float*)d_in[0];
    const float* w_qkv = (const float*)d_in[1];
    const float* w_out = (const float*)d_in[2];
    const float* b_out = (const float*)d_in[3];
    const float* gamma = (const float*)d_in[4];
    const float* beta  = (const float*)d_in[5];
    float* out = (float*)d_out;
    char* ws = (char*)d_ws;

    unsigned short* xb  = (unsigned short*)(ws + OFF_XB);
    unsigned short* wT  = (unsigned short*)(ws + OFF_WT);
    unsigned short* woT = (unsigned short*)(ws + OFF_WOT);
    __bf16* qb  = (__bf16*)(ws + OFF_QB);
    __bf16* kb  = (__bf16*)(ws + OFF_KB);
    __bf16* vT  = (__bf16*)(ws + OFF_VT);
    __bf16* o2tT = (__bf16*)(ws + OFF_O2TT);
    float* stats = (float*)(ws + OFF_ST);

    prep         <<<dim3(384),  256, 0, stream>>>(x, w_qkv, w_out, xb, wT, woT, stats);
    qkv_gemm_mfma<<<dim3(768),  256, 0, stream>>>(xb, (const __bf16*)wT, qb, kb, vT);
    attn_mfma    <<<dim3(512),  256, 0, stream>>>(qb, kb, vT, o2tT);
    out_mfma     <<<dim3(512),  256, 0, stream>>>(o2tT, (const __bf16*)woT, b_out, out, stats);
    gn_finalize  <<<dim3(2048), 256, 0, stream>>>(out, stats, gamma, beta);
}